// Round 1
// baseline (755.189 us; speedup 1.0000x reference)
//
#include <hip/hip_runtime.h>

#define DEVINL __device__ __forceinline__

typedef __attribute__((ext_vector_type(8))) short bf16x8;
typedef __attribute__((ext_vector_type(4))) float f32x4;

DEVINL unsigned short f2bf(float f) {
  unsigned int u = __float_as_uint(f);
  u += 0x7FFFu + ((u >> 16) & 1u);
  return (unsigned short)(u >> 16);
}
DEVINL float sigmf(float x) { return 1.f / (1.f + __expf(-x)); }
DEVINL float tanh_fast(float x) { float e = __expf(2.f * x); return 1.f - 2.f / (e + 1.f); }

// ---------------- conversion / transpose helpers ----------------

__global__ __launch_bounds__(256) void conv_bf16(const float* __restrict__ in,
                                                 unsigned short* __restrict__ out) {
  int id = blockIdx.x * 256 + threadIdx.x;   // 16,384,000 / 4 = 4,096,000 exact
  float4 v = *(const float4*)&in[(size_t)id * 4];
  unsigned int a = (unsigned int)f2bf(v.x) | ((unsigned int)f2bf(v.y) << 16);
  unsigned int b = (unsigned int)f2bf(v.z) | ((unsigned int)f2bf(v.w) << 16);
  *(uint2*)&out[(size_t)id * 4] = make_uint2(a, b);
}

// Whh [1024][256] f32 -> WT [256][1024] bf16
__global__ __launch_bounds__(256) void transpose_bf16(const float* __restrict__ in,
                                                      unsigned short* __restrict__ out) {
  int id = blockIdx.x * 256 + threadIdx.x;   // 262,144 exact
  int j = id & 1023, k = id >> 10;
  out[id] = f2bf(in[j * 256 + k]);
}

// Wih1 [1024][256] f32 -> W1T [256][1024] f32
__global__ __launch_bounds__(256) void transpose_f32(const float* __restrict__ in,
                                                     float* __restrict__ out) {
  int id = blockIdx.x * 256 + threadIdx.x;
  int j = id & 1023, k = id >> 10;
  out[id] = in[j * 256 + k];
}

// ---------------- GCN: separable edge aggregation ----------------
// agg[n,f] = W[f]*A[n] + b[f]*D[n],  A = sum dist*x[src], D = sum dist
__global__ __launch_bounds__(256) void gcn_kernel(
    const float* __restrict__ x, const int* __restrict__ ei, const float* __restrict__ ed,
    const float* __restrict__ Wg, const float* __restrict__ bg,
    unsigned short* __restrict__ G) {
  __shared__ float xs[2000];
  __shared__ float Asum[2000];
  __shared__ float Dsum[2000];
  int bs = blockIdx.x;
  int tid = threadIdx.x;
  for (int i = tid; i < 2000; i += 256) {
    xs[i] = x[(size_t)bs * 2000 + i];
    Asum[i] = 0.f; Dsum[i] = 0.f;
  }
  __syncthreads();
  const int* srcp = ei + (size_t)bs * 32000;
  const int* dstp = srcp + 16000;
  const float* dp = ed + (size_t)bs * 16000;
  for (int e = tid; e < 16000; e += 256) {
    int s = srcp[e], d = dstp[e];
    float w = dp[e];
    atomicAdd(&Asum[d], w * xs[s]);
    atomicAdd(&Dsum[d], w);
  }
  __syncthreads();
  float wreg[8], breg[8];
#pragma unroll
  for (int f = 0; f < 8; ++f) { wreg[f] = Wg[f]; breg[f] = bg[f]; }
  for (int n = tid; n < 2000; n += 256) {
    float a = Asum[n], dd = Dsum[n];
    unsigned int u[4];
#pragma unroll
    for (int p = 0; p < 4; ++p) {
      float v0 = tanh_fast(wreg[2 * p] * a + breg[2 * p] * dd);
      float v1 = tanh_fast(wreg[2 * p + 1] * a + breg[2 * p + 1] * dd);
      u[p] = (unsigned int)f2bf(v0) | ((unsigned int)f2bf(v1) << 16);
    }
    *(uint4*)&G[(size_t)bs * 16000 + n * 8] = make_uint4(u[0], u[1], u[2], u[3]);
  }
}

// ---------------- big MFMA GEMM: Zpart[p] = G @ W0^T (split-K) ----------------
// A [768][16000] bf16 row-major, B [1024][16000] bf16 row-major (NT GEMM)
__global__ __launch_bounds__(256) void gemm_bt(
    const unsigned short* __restrict__ A, const unsigned short* __restrict__ B,
    float* __restrict__ Cp) {
  __shared__ __align__(16) unsigned short As[128 * 32];
  __shared__ __align__(16) unsigned short Bs[128 * 32];
  const int K = 16000;
  int nt = blockIdx.x;   // 0..7
  int mt = blockIdx.y;   // 0..5
  int ks = blockIdx.z;   // 0..9
  int m0 = mt * 128, n0 = nt * 128;
  int tid = threadIdx.x;
  int lane = tid & 63;
  int w = tid >> 6;
  int wm = (w >> 1) * 64, wn = (w & 1) * 64;
  int fr = lane & 15;
  int kg = lane >> 4;

  f32x4 acc[4][4] = {};
  const unsigned short* Ag = A + (size_t)m0 * K + ks * 1600;
  const unsigned short* Bg = B + (size_t)n0 * K + ks * 1600;

  for (int kk = 0; kk < 1600; kk += 32) {
#pragma unroll
    for (int q = 0; q < 2; ++q) {
      int c = q * 256 + tid;
      int row = c >> 2;
      int ko = (c & 3) * 8;
      *(uint4*)&As[c * 8] = *(const uint4*)&Ag[(size_t)row * K + kk + ko];
      *(uint4*)&Bs[c * 8] = *(const uint4*)&Bg[(size_t)row * K + kk + ko];
    }
    __syncthreads();
    bf16x8 aF[4], bF[4];
#pragma unroll
    for (int i = 0; i < 4; ++i)
      aF[i] = *(const bf16x8*)&As[(wm + i * 16 + fr) * 32 + kg * 8];
#pragma unroll
    for (int i = 0; i < 4; ++i)
      bF[i] = *(const bf16x8*)&Bs[(wn + i * 16 + fr) * 32 + kg * 8];
#pragma unroll
    for (int i = 0; i < 4; ++i)
#pragma unroll
      for (int j = 0; j < 4; ++j)
        acc[i][j] = __builtin_amdgcn_mfma_f32_16x16x32_bf16(aF[i], bF[j], acc[i][j], 0, 0, 0);
    __syncthreads();
  }
  float* Co = Cp + (size_t)ks * 768 * 1024;
  int mr = (lane >> 4) * 4;
#pragma unroll
  for (int i = 0; i < 4; ++i)
#pragma unroll
    for (int j = 0; j < 4; ++j) {
      int n = n0 + wn + j * 16 + fr;
#pragma unroll
      for (int r = 0; r < 4; ++r) {
        int m = m0 + wm + i * 16 + mr + r;
        Co[(size_t)m * 1024 + n] = acc[i][j][r];
      }
    }
}

__global__ __launch_bounds__(256) void reduce_z0(
    const float* __restrict__ Cp, const float* __restrict__ bih,
    const float* __restrict__ bhh, float* __restrict__ Z0) {
  int id = blockIdx.x * 256 + threadIdx.x;   // 786,432 exact
  float s = bih[id & 1023] + bhh[id & 1023];
#pragma unroll
  for (int p = 0; p < 10; ++p) s += Cp[(size_t)p * 786432 + id];
  Z0[id] = s;
}

// ---------------- LSTM scan (one block per batch element) ----------------
// Z: [32*24][1024] pre-activations incl. biases; WT: [256][1024] bf16
__global__ __launch_bounds__(512) void lstm_scan(
    const float* __restrict__ Z, const unsigned short* __restrict__ WT,
    float* __restrict__ Hout, float* __restrict__ lastOut) {
  __shared__ float hL[256];
  __shared__ float gL[1024];
  int b = blockIdx.x;
  int tid = threadIdx.x;
  int j0 = tid * 2;
  float c0 = 0.f, c1 = 0.f;
  if (tid < 128) { hL[2 * tid] = 0.f; hL[2 * tid + 1] = 0.f; }
  __syncthreads();
  const unsigned int* wp = (const unsigned int*)WT + tid;  // uint k*512+tid packs j0,j0+1
  for (int t = 0; t < 24; ++t) {
    const float* zrow = Z + (size_t)(b * 24 + t) * 1024;
    float g0 = zrow[j0], g1 = zrow[j0 + 1];
#pragma unroll 8
    for (int k = 0; k < 256; ++k) {
      unsigned int w2 = wp[k * 512];
      float h = hL[k];
      g0 += __uint_as_float(w2 << 16) * h;
      g1 += __uint_as_float(w2 & 0xFFFF0000u) * h;
    }
    gL[j0] = g0; gL[j0 + 1] = g1;
    __syncthreads();
    if (tid < 128) {
#pragma unroll
      for (int q = 0; q < 2; ++q) {
        int n = 2 * tid + q;
        float ig = sigmf(gL[n]);
        float fg = sigmf(gL[256 + n]);
        float gg = tanh_fast(gL[512 + n]);
        float og = sigmf(gL[768 + n]);
        float& c = q ? c1 : c0;
        c = fg * c + ig * gg;
        float h = og * tanh_fast(c);
        hL[n] = h;
        if (Hout) Hout[(size_t)(b * 24 + t) * 256 + n] = h;
        if (lastOut && t == 23) lastOut[b * 256 + n] = tanh_fast(h);
      }
    }
    __syncthreads();
  }
}

// ---------------- Z1 = H1 @ Wih1^T + biases ----------------
__global__ __launch_bounds__(256) void gemm_z1(
    const float* __restrict__ H1, const float* __restrict__ W1T,
    const float* __restrict__ bih, const float* __restrict__ bhh,
    float* __restrict__ Z1) {
  __shared__ float Hs[16][256];
  int tid = threadIdx.x;
  int n = blockIdx.x * 256 + tid;      // < 1024
  int m0 = blockIdx.y * 16;            // < 768
  for (int i = tid; i < 16 * 256; i += 256)
    Hs[i >> 8][i & 255] = H1[(size_t)(m0 + (i >> 8)) * 256 + (i & 255)];
  __syncthreads();
  float acc[16] = {};
  for (int k = 0; k < 256; ++k) {
    float wv = W1T[k * 1024 + n];
#pragma unroll
    for (int m = 0; m < 16; ++m) acc[m] += Hs[m][k] * wv;
  }
  float bias = bih[n] + bhh[n];
#pragma unroll
  for (int m = 0; m < 16; ++m) Z1[(size_t)(m0 + m) * 1024 + n] = acc[m] + bias;
}

// ---------------- fc: out = last @ fc_W^T + fc_b ----------------
__global__ __launch_bounds__(256) void fc_kernel(
    const float* __restrict__ last, const float* __restrict__ fcW,
    const float* __restrict__ fcb, float* __restrict__ out) {
  __shared__ float ls[8][256];
  int tid = threadIdx.x;
  int o = blockIdx.x * 256 + tid;
  int b0 = blockIdx.y * 8;
  for (int i = tid; i < 2048; i += 256)
    ls[i >> 8][i & 255] = last[(b0 + (i >> 8)) * 256 + (i & 255)];
  __syncthreads();
  if (o < 8000) {
    float acc[8] = {};
    for (int k = 0; k < 256; k += 4) {
      float4 wv = *(const float4*)&fcW[(size_t)o * 256 + k];
#pragma unroll
      for (int b = 0; b < 8; ++b)
        acc[b] += wv.x * ls[b][k] + wv.y * ls[b][k + 1] + wv.z * ls[b][k + 2] + wv.w * ls[b][k + 3];
    }
    float bias = fcb[o];
#pragma unroll
    for (int b = 0; b < 8; ++b) out[(size_t)(b0 + b) * 8000 + o] = acc[b] + bias;
  }
}

// ---------------- launch ----------------
extern "C" void kernel_launch(void* const* d_in, const int* in_sizes, int n_in,
                              void* d_out, int out_size, void* d_ws, size_t ws_size,
                              hipStream_t stream) {
  const float* x    = (const float*)d_in[0];
  const int*   ei   = (const int*)d_in[1];
  const float* ed   = (const float*)d_in[2];
  const float* Wg   = (const float*)d_in[3];
  const float* bg   = (const float*)d_in[4];
  const float* Wih0 = (const float*)d_in[5];
  const float* Whh0 = (const float*)d_in[6];
  const float* bih0 = (const float*)d_in[7];
  const float* bhh0 = (const float*)d_in[8];
  const float* Wih1 = (const float*)d_in[9];
  const float* Whh1 = (const float*)d_in[10];
  const float* bih1 = (const float*)d_in[11];
  const float* bhh1 = (const float*)d_in[12];
  const float* fcW  = (const float*)d_in[13];
  const float* fcb  = (const float*)d_in[14];
  float* out = (float*)d_out;

  char* ws = (char*)d_ws;
  unsigned short* Gbf  = (unsigned short*)(ws);              // 24,576,000 B
  unsigned short* W0bf = (unsigned short*)(ws + 24576000);   // 32,768,000 B
  float* Zpart = (float*)(ws + 57344000);                    // 31,457,280 B (10 partials)
  float* Z0    = (float*)(ws + 88801280);                    //  3,145,728 B
  unsigned short* WT0 = (unsigned short*)(ws + 91947008);    //    524,288 B
  unsigned short* WT1 = (unsigned short*)(ws + 92471296);    //    524,288 B
  float* W1T   = (float*)(ws + 92995584);                    //  1,048,576 B
  float* H1    = (float*)(ws + 94044160);                    //    786,432 B
  float* Z1    = (float*)(ws + 94830592);                    //  3,145,728 B
  float* lastb = (float*)(ws + 97976320);                    //     32,768 B (end ~98 MB)

  conv_bf16<<<16000, 256, 0, stream>>>(Wih0, W0bf);
  transpose_bf16<<<1024, 256, 0, stream>>>(Whh0, WT0);
  transpose_bf16<<<1024, 256, 0, stream>>>(Whh1, WT1);
  transpose_f32<<<1024, 256, 0, stream>>>(Wih1, W1T);
  gcn_kernel<<<768, 256, 0, stream>>>(x, ei, ed, Wg, bg, Gbf);
  gemm_bt<<<dim3(8, 6, 10), 256, 0, stream>>>(Gbf, W0bf, Zpart);
  reduce_z0<<<3072, 256, 0, stream>>>(Zpart, bih0, bhh0, Z0);
  lstm_scan<<<32, 512, 0, stream>>>(Z0, WT0, H1, nullptr);
  gemm_z1<<<dim3(4, 48), 256, 0, stream>>>(H1, W1T, bih1, bhh1, Z1);
  lstm_scan<<<32, 512, 0, stream>>>(Z1, WT1, nullptr, lastb);
  fc_kernel<<<dim3(32, 4), 256, 0, stream>>>(lastb, fcW, fcb, out);
}

// Round 2
// 514.349 us; speedup vs baseline: 1.4682x; 1.4682x over previous
//
#include <hip/hip_runtime.h>

#define DEVINL __device__ __forceinline__

typedef __attribute__((ext_vector_type(8))) short bf16x8;
typedef __attribute__((ext_vector_type(4))) float f32x4;

DEVINL unsigned short f2bf(float f) {
  unsigned int u = __float_as_uint(f);
  u += 0x7FFFu + ((u >> 16) & 1u);
  return (unsigned short)(u >> 16);
}
DEVINL float sigmf(float x) { return 1.f / (1.f + __expf(-x)); }
DEVINL float tanh_fast(float x) { float e = __expf(2.f * x); return 1.f - 2.f / (e + 1.f); }

// ---------------- conversion / pack helpers ----------------

__global__ __launch_bounds__(256) void conv_bf16(const float* __restrict__ in,
                                                 unsigned short* __restrict__ out) {
  int id = blockIdx.x * 256 + threadIdx.x;   // 16,384,000 / 4 = 4,096,000 exact
  float4 v = *(const float4*)&in[(size_t)id * 4];
  unsigned int a = (unsigned int)f2bf(v.x) | ((unsigned int)f2bf(v.y) << 16);
  unsigned int b = (unsigned int)f2bf(v.z) | ((unsigned int)f2bf(v.w) << 16);
  *(uint2*)&out[(size_t)id * 4] = make_uint2(a, b);
}

// Whh [1024][256] f32 -> WP [128][1024] uint, packing bf16(Whh[j][2k2]),bf16(Whh[j][2k2+1])
__global__ __launch_bounds__(256) void pack_whh(const float* __restrict__ in,
                                                unsigned int* __restrict__ out) {
  int id = blockIdx.x * 256 + threadIdx.x;   // 131,072 exact
  int j = id & 1023, k2 = id >> 10;
  float2 v = *(const float2*)&in[j * 256 + k2 * 2];
  out[k2 * 1024 + j] = (unsigned int)f2bf(v.x) | ((unsigned int)f2bf(v.y) << 16);
}

// Wih1 [1024][256] f32 -> W1T [256][1024] f32
__global__ __launch_bounds__(256) void transpose_f32(const float* __restrict__ in,
                                                     float* __restrict__ out) {
  int id = blockIdx.x * 256 + threadIdx.x;
  int j = id & 1023, k = id >> 10;
  out[id] = in[j * 256 + k];
}

// ---------------- GCN: separable edge aggregation ----------------
__global__ __launch_bounds__(256) void gcn_kernel(
    const float* __restrict__ x, const int* __restrict__ ei, const float* __restrict__ ed,
    const float* __restrict__ Wg, const float* __restrict__ bg,
    unsigned short* __restrict__ G) {
  __shared__ float xs[2000];
  __shared__ float Asum[2000];
  __shared__ float Dsum[2000];
  int bs = blockIdx.x;
  int tid = threadIdx.x;
  for (int i = tid; i < 2000; i += 256) {
    xs[i] = x[(size_t)bs * 2000 + i];
    Asum[i] = 0.f; Dsum[i] = 0.f;
  }
  __syncthreads();
  const int* srcp = ei + (size_t)bs * 32000;
  const int* dstp = srcp + 16000;
  const float* dp = ed + (size_t)bs * 16000;
  for (int e = tid; e < 16000; e += 256) {
    int s = srcp[e], d = dstp[e];
    float w = dp[e];
    atomicAdd(&Asum[d], w * xs[s]);
    atomicAdd(&Dsum[d], w);
  }
  __syncthreads();
  float wreg[8], breg[8];
#pragma unroll
  for (int f = 0; f < 8; ++f) { wreg[f] = Wg[f]; breg[f] = bg[f]; }
  for (int n = tid; n < 2000; n += 256) {
    float a = Asum[n], dd = Dsum[n];
    unsigned int u[4];
#pragma unroll
    for (int p = 0; p < 4; ++p) {
      float v0 = tanh_fast(wreg[2 * p] * a + breg[2 * p] * dd);
      float v1 = tanh_fast(wreg[2 * p + 1] * a + breg[2 * p + 1] * dd);
      u[p] = (unsigned int)f2bf(v0) | ((unsigned int)f2bf(v1) << 16);
    }
    *(uint4*)&G[(size_t)bs * 16000 + n * 8] = make_uint4(u[0], u[1], u[2], u[3]);
  }
}

// ---------------- big MFMA GEMM: Zpart[p] = G @ W0^T (split-K) ----------------
__global__ __launch_bounds__(256) void gemm_bt(
    const unsigned short* __restrict__ A, const unsigned short* __restrict__ B,
    float* __restrict__ Cp) {
  __shared__ __align__(16) unsigned short As[128 * 32];
  __shared__ __align__(16) unsigned short Bs[128 * 32];
  const int K = 16000;
  int nt = blockIdx.x;
  int mt = blockIdx.y;
  int ks = blockIdx.z;
  int m0 = mt * 128, n0 = nt * 128;
  int tid = threadIdx.x;
  int lane = tid & 63;
  int w = tid >> 6;
  int wm = (w >> 1) * 64, wn = (w & 1) * 64;
  int fr = lane & 15;
  int kg = lane >> 4;

  f32x4 acc[4][4] = {};
  const unsigned short* Ag = A + (size_t)m0 * K + ks * 1600;
  const unsigned short* Bg = B + (size_t)n0 * K + ks * 1600;

  for (int kk = 0; kk < 1600; kk += 32) {
#pragma unroll
    for (int q = 0; q < 2; ++q) {
      int c = q * 256 + tid;
      int row = c >> 2;
      int ko = (c & 3) * 8;
      *(uint4*)&As[c * 8] = *(const uint4*)&Ag[(size_t)row * K + kk + ko];
      *(uint4*)&Bs[c * 8] = *(const uint4*)&Bg[(size_t)row * K + kk + ko];
    }
    __syncthreads();
    bf16x8 aF[4], bF[4];
#pragma unroll
    for (int i = 0; i < 4; ++i)
      aF[i] = *(const bf16x8*)&As[(wm + i * 16 + fr) * 32 + kg * 8];
#pragma unroll
    for (int i = 0; i < 4; ++i)
      bF[i] = *(const bf16x8*)&Bs[(wn + i * 16 + fr) * 32 + kg * 8];
#pragma unroll
    for (int i = 0; i < 4; ++i)
#pragma unroll
      for (int j = 0; j < 4; ++j)
        acc[i][j] = __builtin_amdgcn_mfma_f32_16x16x32_bf16(aF[i], bF[j], acc[i][j], 0, 0, 0);
    __syncthreads();
  }
  float* Co = Cp + (size_t)ks * 768 * 1024;
  int mr = (lane >> 4) * 4;
#pragma unroll
  for (int i = 0; i < 4; ++i)
#pragma unroll
    for (int j = 0; j < 4; ++j) {
      int n = n0 + wn + j * 16 + fr;
#pragma unroll
      for (int r = 0; r < 4; ++r) {
        int m = m0 + wm + i * 16 + mr + r;
        Co[(size_t)m * 1024 + n] = acc[i][j][r];
      }
    }
}

__global__ __launch_bounds__(256) void reduce_z0(
    const float* __restrict__ Cp, const float* __restrict__ bih,
    const float* __restrict__ bhh, float* __restrict__ Z0) {
  int id = blockIdx.x * 256 + threadIdx.x;   // 786,432 exact
  float s = bih[id & 1023] + bhh[id & 1023];
#pragma unroll
  for (int p = 0; p < 10; ++p) s += Cp[(size_t)p * 786432 + id];
  Z0[id] = s;
}

// ---------------- LSTM scan: 4 blocks per batch, LDS-resident weights ----------------
// Z: [32*24][1024] preactivations (biases included). WP: [128][1024] packed bf16 k-pairs
// of Whh^T. Hex: [32][24][256] h history / exchange buffer. cnt: [32][24] flags (zeroed).
__global__ __launch_bounds__(512) void lstm_scan_sync(
    const float* __restrict__ Z, const unsigned int* __restrict__ WP,
    float* __restrict__ Hex, int* __restrict__ cnt, float* __restrict__ lastOut) {
  __shared__ unsigned int Wl[128 * 256];   // 128 KB: this block's 256 gate columns
  __shared__ float h_lds[256];
  __shared__ float g_lds[512];
  int b  = blockIdx.x >> 2;     // batch
  int g  = blockIdx.x & 3;      // group (owns gate cols {q*256 + g*64 + 0..63})
  int tid = threadIdx.x;
  int c  = tid & 255;           // local column 0..255
  int kh = tid >> 8;            // k-half 0/1
  int q  = c >> 6;              // gate type
  int r  = c & 63;
  int j0 = g * 64;
  int col = q * 256 + j0 + r;   // global gate column

  // stage weight slice into LDS (once)
  for (int idx = tid; idx < 128 * 256; idx += 512) {
    int k2 = idx >> 8;
    int cc = idx & 255;
    Wl[idx] = WP[k2 * 1024 + (cc >> 6) * 256 + j0 + (cc & 63)];
  }
  if (tid < 256) h_lds[tid] = 0.f;
  __syncthreads();

  float cst = 0.f;
  const size_t b24 = (size_t)b * 24;
  const float* Zb = Z + b24 * 1024 + col;
  const int kbase = kh * 64;

  for (int t = 0; t < 24; ++t) {
    float acc = (kh == 0) ? Zb[t * 1024] : 0.f;
#pragma unroll 8
    for (int k2 = 0; k2 < 64; ++k2) {
      int kk = kbase + k2;
      unsigned int w2 = Wl[kk * 256 + c];
      float2 h2 = *(const float2*)&h_lds[kk * 2];
      acc += __uint_as_float(w2 << 16) * h2.x + __uint_as_float(w2 & 0xFFFF0000u) * h2.y;
    }
    g_lds[tid] = acc;
    __syncthreads();
    if (tid < 64) {
      float ig = sigmf(g_lds[tid]       + g_lds[tid + 256]);
      float fg = sigmf(g_lds[tid + 64]  + g_lds[tid + 320]);
      float gg = tanh_fast(g_lds[tid + 128] + g_lds[tid + 384]);
      float og = sigmf(g_lds[tid + 192] + g_lds[tid + 448]);
      cst = fg * cst + ig * gg;
      float h = og * tanh_fast(cst);
      __hip_atomic_store(&Hex[(b24 + t) * 256 + j0 + tid], h,
                         __ATOMIC_RELAXED, __HIP_MEMORY_SCOPE_AGENT);
      if (lastOut != nullptr && t == 23)
        lastOut[b * 256 + j0 + tid] = tanh_fast(h);
    }
    if (t == 23) break;
    __syncthreads();   // drains the Hex stores (vmcnt 0) before the flag add
    if (tid == 0) {
      __hip_atomic_fetch_add(&cnt[b * 24 + t], 1, __ATOMIC_RELEASE, __HIP_MEMORY_SCOPE_AGENT);
      while (__hip_atomic_load(&cnt[b * 24 + t], __ATOMIC_ACQUIRE,
                               __HIP_MEMORY_SCOPE_AGENT) < 4)
        __builtin_amdgcn_s_sleep(2);
    }
    __syncthreads();
    if (tid < 256)
      h_lds[tid] = __hip_atomic_load(&Hex[(b24 + t) * 256 + tid],
                                     __ATOMIC_RELAXED, __HIP_MEMORY_SCOPE_AGENT);
    __syncthreads();
  }
}

// ---------------- Z1 = H1 @ Wih1^T + biases ----------------
__global__ __launch_bounds__(256) void gemm_z1(
    const float* __restrict__ H1, const float* __restrict__ W1T,
    const float* __restrict__ bih, const float* __restrict__ bhh,
    float* __restrict__ Z1) {
  __shared__ float Hs[16][256];
  int tid = threadIdx.x;
  int n = blockIdx.x * 256 + tid;
  int m0 = blockIdx.y * 16;
  for (int i = tid; i < 16 * 256; i += 256)
    Hs[i >> 8][i & 255] = H1[(size_t)(m0 + (i >> 8)) * 256 + (i & 255)];
  __syncthreads();
  float acc[16] = {};
  for (int k = 0; k < 256; ++k) {
    float wv = W1T[k * 1024 + n];
#pragma unroll
    for (int m = 0; m < 16; ++m) acc[m] += Hs[m][k] * wv;
  }
  float bias = bih[n] + bhh[n];
#pragma unroll
  for (int m = 0; m < 16; ++m) Z1[(size_t)(m0 + m) * 1024 + n] = acc[m] + bias;
}

// ---------------- fc: out = last @ fc_W^T + fc_b ----------------
__global__ __launch_bounds__(256) void fc_kernel(
    const float* __restrict__ last, const float* __restrict__ fcW,
    const float* __restrict__ fcb, float* __restrict__ out) {
  __shared__ float ls[8][256];
  int tid = threadIdx.x;
  int o = blockIdx.x * 256 + tid;
  int b0 = blockIdx.y * 8;
  for (int i = tid; i < 2048; i += 256)
    ls[i >> 8][i & 255] = last[(b0 + (i >> 8)) * 256 + (i & 255)];
  __syncthreads();
  if (o < 8000) {
    float acc[8] = {};
    for (int k = 0; k < 256; k += 4) {
      float4 wv = *(const float4*)&fcW[(size_t)o * 256 + k];
#pragma unroll
      for (int b = 0; b < 8; ++b)
        acc[b] += wv.x * ls[b][k] + wv.y * ls[b][k + 1] + wv.z * ls[b][k + 2] + wv.w * ls[b][k + 3];
    }
    float bias = fcb[o];
#pragma unroll
    for (int b = 0; b < 8; ++b) out[(size_t)(b0 + b) * 8000 + o] = acc[b] + bias;
  }
}

// ---------------- launch ----------------
extern "C" void kernel_launch(void* const* d_in, const int* in_sizes, int n_in,
                              void* d_out, int out_size, void* d_ws, size_t ws_size,
                              hipStream_t stream) {
  const float* x    = (const float*)d_in[0];
  const int*   ei   = (const int*)d_in[1];
  const float* ed   = (const float*)d_in[2];
  const float* Wg   = (const float*)d_in[3];
  const float* bg   = (const float*)d_in[4];
  const float* Wih0 = (const float*)d_in[5];
  const float* Whh0 = (const float*)d_in[6];
  const float* bih0 = (const float*)d_in[7];
  const float* bhh0 = (const float*)d_in[8];
  const float* Wih1 = (const float*)d_in[9];
  const float* Whh1 = (const float*)d_in[10];
  const float* bih1 = (const float*)d_in[11];
  const float* bhh1 = (const float*)d_in[12];
  const float* fcW  = (const float*)d_in[13];
  const float* fcb  = (const float*)d_in[14];
  float* out = (float*)d_out;

  char* ws = (char*)d_ws;
  unsigned short* Gbf  = (unsigned short*)(ws);              // 24,576,000
  unsigned short* W0bf = (unsigned short*)(ws + 24576000);   // 32,768,000
  float* Zpart = (float*)(ws + 57344000);                    // 31,457,280
  float* Z0    = (float*)(ws + 88801280);                    //  3,145,728
  unsigned int* WP0 = (unsigned int*)(ws + 91947008);        //    524,288
  unsigned int* WP1 = (unsigned int*)(ws + 92471296);        //    524,288
  float* W1T   = (float*)(ws + 92995584);                    //  1,048,576
  float* H1    = (float*)(ws + 94044160);                    //    786,432
  float* Z1    = (float*)(ws + 94830592);                    //  3,145,728
  float* lastb = (float*)(ws + 97976320);                    //     32,768
  float* Hs1   = (float*)(ws + 98009088);                    //    786,432
  int*   cnt   = (int*)(ws + 98795520);                      //      8,192  (end ~98.8 MB)

  hipMemsetAsync(cnt, 0, 8192, stream);
  conv_bf16<<<16000, 256, 0, stream>>>(Wih0, W0bf);
  pack_whh<<<512, 256, 0, stream>>>(Whh0, WP0);
  pack_whh<<<512, 256, 0, stream>>>(Whh1, WP1);
  transpose_f32<<<1024, 256, 0, stream>>>(Wih1, W1T);
  gcn_kernel<<<768, 256, 0, stream>>>(x, ei, ed, Wg, bg, Gbf);
  gemm_bt<<<dim3(8, 6, 10), 256, 0, stream>>>(Gbf, W0bf, Zpart);
  reduce_z0<<<3072, 256, 0, stream>>>(Zpart, bih0, bhh0, Z0);
  lstm_scan_sync<<<128, 512, 0, stream>>>(Z0, WP0, H1, cnt, nullptr);
  gemm_z1<<<dim3(4, 48), 256, 0, stream>>>(H1, W1T, bih1, bhh1, Z1);
  lstm_scan_sync<<<128, 512, 0, stream>>>(Z1, WP1, Hs1, cnt + 768, lastb);
  fc_kernel<<<dim3(32, 4), 256, 0, stream>>>(lastb, fcW, fcb, out);
}

// Round 4
// 511.066 us; speedup vs baseline: 1.4777x; 1.0064x over previous
//
#include <hip/hip_runtime.h>

#define DEVINL __device__ __forceinline__

typedef __attribute__((ext_vector_type(8))) short bf16x8;
typedef __attribute__((ext_vector_type(4))) float f32x4;

DEVINL unsigned short f2bf(float f) {
  unsigned int u = __float_as_uint(f);
  u += 0x7FFFu + ((u >> 16) & 1u);
  return (unsigned short)(u >> 16);
}
DEVINL float sigmf(float x) { return 1.f / (1.f + __expf(-x)); }
DEVINL float tanh_fast(float x) { float e = __expf(2.f * x); return 1.f - 2.f / (e + 1.f); }

// ---------------- conversion / pack helpers ----------------

__global__ __launch_bounds__(256) void conv_bf16(const float* __restrict__ in,
                                                 unsigned short* __restrict__ out) {
  int id = blockIdx.x * 256 + threadIdx.x;   // 16,384,000 / 4 = 4,096,000 exact
  float4 v = *(const float4*)&in[(size_t)id * 4];
  unsigned int a = (unsigned int)f2bf(v.x) | ((unsigned int)f2bf(v.y) << 16);
  unsigned int b = (unsigned int)f2bf(v.z) | ((unsigned int)f2bf(v.w) << 16);
  *(uint2*)&out[(size_t)id * 4] = make_uint2(a, b);
}

// Whh [1024][256] f32 -> WP [128][1024] uint, packing bf16(Whh[j][2k2]),bf16(Whh[j][2k2+1])
__global__ __launch_bounds__(256) void pack_whh(const float* __restrict__ in,
                                                unsigned int* __restrict__ out) {
  int id = blockIdx.x * 256 + threadIdx.x;   // 131,072 exact
  int j = id & 1023, k2 = id >> 10;
  float2 v = *(const float2*)&in[j * 256 + k2 * 2];
  out[k2 * 1024 + j] = (unsigned int)f2bf(v.x) | ((unsigned int)f2bf(v.y) << 16);
}

// Wih1 [1024][256] f32 -> W1T [256][1024] f32
__global__ __launch_bounds__(256) void transpose_f32(const float* __restrict__ in,
                                                     float* __restrict__ out) {
  int id = blockIdx.x * 256 + threadIdx.x;
  int j = id & 1023, k = id >> 10;
  out[id] = in[j * 256 + k];
}

// ---------------- GCN: separable edge aggregation (1024 threads, 32 waves/CU) ----------------
// agg[n,f] = W[f]*A[n] + b[f]*D[n],  A = sum dist*x[src], D = sum dist
__global__ __launch_bounds__(1024) void gcn_kernel(
    const float* __restrict__ x, const int* __restrict__ ei, const float* __restrict__ ed,
    const float* __restrict__ Wg, const float* __restrict__ bg,
    unsigned short* __restrict__ G) {
  __shared__ float xs[2000];
  __shared__ float Asum[2000];
  __shared__ float Dsum[2000];
  int bs = blockIdx.x;
  int tid = threadIdx.x;
  for (int i = tid; i < 2000; i += 1024) {
    xs[i] = x[(size_t)bs * 2000 + i];
    Asum[i] = 0.f; Dsum[i] = 0.f;
  }
  __syncthreads();
  const int* srcp = ei + (size_t)bs * 32000;
  const int* dstp = srcp + 16000;
  const float* dp = ed + (size_t)bs * 16000;
  // 16000 edges = 4000 int4 groups; 1024 threads -> ~4 iterations
  for (int i = tid; i < 4000; i += 1024) {
    int4 s4 = ((const int4*)srcp)[i];
    int4 d4 = ((const int4*)dstp)[i];
    float4 w4 = ((const float4*)dp)[i];
    atomicAdd(&Asum[d4.x], w4.x * xs[s4.x]);
    atomicAdd(&Dsum[d4.x], w4.x);
    atomicAdd(&Asum[d4.y], w4.y * xs[s4.y]);
    atomicAdd(&Dsum[d4.y], w4.y);
    atomicAdd(&Asum[d4.z], w4.z * xs[s4.z]);
    atomicAdd(&Dsum[d4.z], w4.z);
    atomicAdd(&Asum[d4.w], w4.w * xs[s4.w]);
    atomicAdd(&Dsum[d4.w], w4.w);
  }
  __syncthreads();
  float wreg[8], breg[8];
#pragma unroll
  for (int f = 0; f < 8; ++f) { wreg[f] = Wg[f]; breg[f] = bg[f]; }
  for (int n = tid; n < 2000; n += 1024) {
    float a = Asum[n], dd = Dsum[n];
    unsigned int u[4];
#pragma unroll
    for (int p = 0; p < 4; ++p) {
      float v0 = tanh_fast(wreg[2 * p] * a + breg[2 * p] * dd);
      float v1 = tanh_fast(wreg[2 * p + 1] * a + breg[2 * p + 1] * dd);
      u[p] = (unsigned int)f2bf(v0) | ((unsigned int)f2bf(v1) << 16);
    }
    *(uint4*)&G[(size_t)bs * 16000 + n * 8] = make_uint4(u[0], u[1], u[2], u[3]);
  }
}

// ---------------- big MFMA GEMM: Zpart[p] = G @ W0^T (split-K) ----------------
__global__ __launch_bounds__(256) void gemm_bt(
    const unsigned short* __restrict__ A, const unsigned short* __restrict__ B,
    float* __restrict__ Cp) {
  __shared__ __align__(16) unsigned short As[128 * 32];
  __shared__ __align__(16) unsigned short Bs[128 * 32];
  const int K = 16000;
  int nt = blockIdx.x;
  int mt = blockIdx.y;
  int ks = blockIdx.z;
  int m0 = mt * 128, n0 = nt * 128;
  int tid = threadIdx.x;
  int lane = tid & 63;
  int w = tid >> 6;
  int wm = (w >> 1) * 64, wn = (w & 1) * 64;
  int fr = lane & 15;
  int kg = lane >> 4;

  f32x4 acc[4][4] = {};
  const unsigned short* Ag = A + (size_t)m0 * K + ks * 1600;
  const unsigned short* Bg = B + (size_t)n0 * K + ks * 1600;

  for (int kk = 0; kk < 1600; kk += 32) {
#pragma unroll
    for (int q = 0; q < 2; ++q) {
      int c = q * 256 + tid;
      int row = c >> 2;
      int ko = (c & 3) * 8;
      *(uint4*)&As[c * 8] = *(const uint4*)&Ag[(size_t)row * K + kk + ko];
      *(uint4*)&Bs[c * 8] = *(const uint4*)&Bg[(size_t)row * K + kk + ko];
    }
    __syncthreads();
    bf16x8 aF[4], bF[4];
#pragma unroll
    for (int i = 0; i < 4; ++i)
      aF[i] = *(const bf16x8*)&As[(wm + i * 16 + fr) * 32 + kg * 8];
#pragma unroll
    for (int i = 0; i < 4; ++i)
      bF[i] = *(const bf16x8*)&Bs[(wn + i * 16 + fr) * 32 + kg * 8];
#pragma unroll
    for (int i = 0; i < 4; ++i)
#pragma unroll
      for (int j = 0; j < 4; ++j)
        acc[i][j] = __builtin_amdgcn_mfma_f32_16x16x32_bf16(aF[i], bF[j], acc[i][j], 0, 0, 0);
    __syncthreads();
  }
  float* Co = Cp + (size_t)ks * 768 * 1024;
  int mr = (lane >> 4) * 4;
#pragma unroll
  for (int i = 0; i < 4; ++i)
#pragma unroll
    for (int j = 0; j < 4; ++j) {
      int n = n0 + wn + j * 16 + fr;
#pragma unroll
      for (int r = 0; r < 4; ++r) {
        int m = m0 + wm + i * 16 + mr + r;
        Co[(size_t)m * 1024 + n] = acc[i][j][r];
      }
    }
}

__global__ __launch_bounds__(256) void reduce_z0(
    const float* __restrict__ Cp, const float* __restrict__ bih,
    const float* __restrict__ bhh, float* __restrict__ Z0) {
  int id = blockIdx.x * 256 + threadIdx.x;   // 786,432 exact
  float s = bih[id & 1023] + bhh[id & 1023];
#pragma unroll
  for (int p = 0; p < 10; ++p) s += Cp[(size_t)p * 786432 + id];
  Z0[id] = s;
}

// ---------------- LSTM scan: 4 blocks per batch, LDS-resident weights ----------------
__global__ __launch_bounds__(512) void lstm_scan_sync(
    const float* __restrict__ Z, const unsigned int* __restrict__ WP,
    float* __restrict__ Hex, int* __restrict__ cnt, float* __restrict__ lastOut) {
  __shared__ unsigned int Wl[128 * 256];   // 128 KB: this block's 256 gate columns
  __shared__ float h_lds[256];
  __shared__ float g_lds[512];
  int b  = blockIdx.x >> 2;     // batch
  int g  = blockIdx.x & 3;      // group (owns gate cols {q*256 + g*64 + 0..63})
  int tid = threadIdx.x;
  int c  = tid & 255;           // local column 0..255
  int kh = tid >> 8;            // k-half 0/1
  int q  = c >> 6;              // gate type
  int r  = c & 63;
  int j0 = g * 64;
  int col = q * 256 + j0 + r;   // global gate column

  for (int idx = tid; idx < 128 * 256; idx += 512) {
    int k2 = idx >> 8;
    int cc = idx & 255;
    Wl[idx] = WP[k2 * 1024 + (cc >> 6) * 256 + j0 + (cc & 63)];
  }
  if (tid < 256) h_lds[tid] = 0.f;
  __syncthreads();

  float cst = 0.f;
  const size_t b24 = (size_t)b * 24;
  const float* Zb = Z + b24 * 1024 + col;
  const int kbase = kh * 64;

  for (int t = 0; t < 24; ++t) {
    float acc = (kh == 0) ? Zb[t * 1024] : 0.f;
#pragma unroll 8
    for (int k2 = 0; k2 < 64; ++k2) {
      int kk = kbase + k2;
      unsigned int w2 = Wl[kk * 256 + c];
      float2 h2 = *(const float2*)&h_lds[kk * 2];
      acc += __uint_as_float(w2 << 16) * h2.x + __uint_as_float(w2 & 0xFFFF0000u) * h2.y;
    }
    g_lds[tid] = acc;
    __syncthreads();
    if (tid < 64) {
      float ig = sigmf(g_lds[tid]       + g_lds[tid + 256]);
      float fg = sigmf(g_lds[tid + 64]  + g_lds[tid + 320]);
      float gg = tanh_fast(g_lds[tid + 128] + g_lds[tid + 384]);
      float og = sigmf(g_lds[tid + 192] + g_lds[tid + 448]);
      cst = fg * cst + ig * gg;
      float h = og * tanh_fast(cst);
      __hip_atomic_store(&Hex[(b24 + t) * 256 + j0 + tid], h,
                         __ATOMIC_RELAXED, __HIP_MEMORY_SCOPE_AGENT);
      if (lastOut != nullptr && t == 23)
        lastOut[b * 256 + j0 + tid] = tanh_fast(h);
    }
    if (t == 23) break;
    __syncthreads();
    if (tid == 0) {
      __hip_atomic_fetch_add(&cnt[b * 24 + t], 1, __ATOMIC_RELEASE, __HIP_MEMORY_SCOPE_AGENT);
      while (__hip_atomic_load(&cnt[b * 24 + t], __ATOMIC_ACQUIRE,
                               __HIP_MEMORY_SCOPE_AGENT) < 4)
        __builtin_amdgcn_s_sleep(2);
    }
    __syncthreads();
    if (tid < 256)
      h_lds[tid] = __hip_atomic_load(&Hex[(b24 + t) * 256 + tid],
                                     __ATOMIC_RELAXED, __HIP_MEMORY_SCOPE_AGENT);
    __syncthreads();
  }
}

// ---------------- Z1 = H1 @ Wih1^T + biases ----------------
__global__ __launch_bounds__(256) void gemm_z1(
    const float* __restrict__ H1, const float* __restrict__ W1T,
    const float* __restrict__ bih, const float* __restrict__ bhh,
    float* __restrict__ Z1) {
  __shared__ float Hs[16][256];
  int tid = threadIdx.x;
  int n = blockIdx.x * 256 + tid;
  int m0 = blockIdx.y * 16;
  for (int i = tid; i < 16 * 256; i += 256)
    Hs[i >> 8][i & 255] = H1[(size_t)(m0 + (i >> 8)) * 256 + (i & 255)];
  __syncthreads();
  float acc[16] = {};
  for (int k = 0; k < 256; ++k) {
    float wv = W1T[k * 1024 + n];
#pragma unroll
    for (int m = 0; m < 16; ++m) acc[m] += Hs[m][k] * wv;
  }
  float bias = bih[n] + bhh[n];
#pragma unroll
  for (int m = 0; m < 16; ++m) Z1[(size_t)(m0 + m) * 1024 + n] = acc[m] + bias;
}

// ---------------- fc: out = last @ fc_W^T + fc_b ----------------
__global__ __launch_bounds__(256) void fc_kernel(
    const float* __restrict__ last, const float* __restrict__ fcW,
    const float* __restrict__ fcb, float* __restrict__ out) {
  __shared__ float ls[8][256];
  int tid = threadIdx.x;
  int o = blockIdx.x * 256 + tid;
  int b0 = blockIdx.y * 8;
  for (int i = tid; i < 2048; i += 256)
    ls[i >> 8][i & 255] = last[(b0 + (i >> 8)) * 256 + (i & 255)];
  __syncthreads();
  if (o < 8000) {
    float acc[8] = {};
    for (int k = 0; k < 256; k += 4) {
      float4 wv = *(const float4*)&fcW[(size_t)o * 256 + k];
#pragma unroll
      for (int b = 0; b < 8; ++b)
        acc[b] += wv.x * ls[b][k] + wv.y * ls[b][k + 1] + wv.z * ls[b][k + 2] + wv.w * ls[b][k + 3];
    }
    float bias = fcb[o];
#pragma unroll
    for (int b = 0; b < 8; ++b) out[(size_t)(b0 + b) * 8000 + o] = acc[b] + bias;
  }
}

// ---------------- launch ----------------
extern "C" void kernel_launch(void* const* d_in, const int* in_sizes, int n_in,
                              void* d_out, int out_size, void* d_ws, size_t ws_size,
                              hipStream_t stream) {
  const float* x    = (const float*)d_in[0];
  const int*   ei   = (const int*)d_in[1];
  const float* ed   = (const float*)d_in[2];
  const float* Wg   = (const float*)d_in[3];
  const float* bg   = (const float*)d_in[4];
  const float* Wih0 = (const float*)d_in[5];
  const float* Whh0 = (const float*)d_in[6];
  const float* bih0 = (const float*)d_in[7];
  const float* bhh0 = (const float*)d_in[8];
  const float* Wih1 = (const float*)d_in[9];
  const float* Whh1 = (const float*)d_in[10];
  const float* bih1 = (const float*)d_in[11];
  const float* bhh1 = (const float*)d_in[12];
  const float* fcW  = (const float*)d_in[13];
  const float* fcb  = (const float*)d_in[14];
  float* out = (float*)d_out;

  char* ws = (char*)d_ws;
  unsigned short* Gbf  = (unsigned short*)(ws);              // 24,576,000
  unsigned short* W0bf = (unsigned short*)(ws + 24576000);   // 32,768,000
  float* Zpart = (float*)(ws + 57344000);                    // 31,457,280
  float* Z0    = (float*)(ws + 88801280);                    //  3,145,728
  unsigned int* WP0 = (unsigned int*)(ws + 91947008);        //    524,288
  unsigned int* WP1 = (unsigned int*)(ws + 92471296);        //    524,288
  float* W1T   = (float*)(ws + 92995584);                    //  1,048,576
  float* H1    = (float*)(ws + 94044160);                    //    786,432
  float* Z1    = (float*)(ws + 94830592);                    //  3,145,728
  float* lastb = (float*)(ws + 97976320);                    //     32,768
  float* Hs1   = (float*)(ws + 98009088);                    //    786,432
  int*   cnt   = (int*)(ws + 98795520);                      //      8,192  (end ~98.8 MB)

  hipMemsetAsync(cnt, 0, 8192, stream);
  conv_bf16<<<16000, 256, 0, stream>>>(Wih0, W0bf);
  pack_whh<<<512, 256, 0, stream>>>(Whh0, WP0);
  pack_whh<<<512, 256, 0, stream>>>(Whh1, WP1);
  transpose_f32<<<1024, 256, 0, stream>>>(Wih1, W1T);
  gcn_kernel<<<768, 1024, 0, stream>>>(x, ei, ed, Wg, bg, Gbf);
  gemm_bt<<<dim3(8, 6, 10), 256, 0, stream>>>(Gbf, W0bf, Zpart);
  reduce_z0<<<3072, 256, 0, stream>>>(Zpart, bih0, bhh0, Z0);
  lstm_scan_sync<<<128, 512, 0, stream>>>(Z0, WP0, H1, cnt, nullptr);
  gemm_z1<<<dim3(4, 48), 256, 0, stream>>>(H1, W1T, bih1, bhh1, Z1);
  lstm_scan_sync<<<128, 512, 0, stream>>>(Z1, WP1, Hs1, cnt + 768, lastb);
  fc_kernel<<<dim3(32, 4), 256, 0, stream>>>(lastb, fcW, fcb, out);
}

// Round 5
// 412.710 us; speedup vs baseline: 1.8298x; 1.2383x over previous
//
#include <hip/hip_runtime.h>

#define DEVINL __device__ __forceinline__

typedef __attribute__((ext_vector_type(8))) short bf16x8;
typedef __attribute__((ext_vector_type(4))) float f32x4;

DEVINL unsigned short f2bf(float f) {
  unsigned int u = __float_as_uint(f);
  u += 0x7FFFu + ((u >> 16) & 1u);
  return (unsigned short)(u >> 16);
}
DEVINL float sigmf(float x) { return 1.f / (1.f + __expf(-x)); }
DEVINL float tanh_fast(float x) { float e = __expf(2.f * x); return 1.f - 2.f / (e + 1.f); }

// ---------------- conversion / pack helpers ----------------

__global__ __launch_bounds__(256) void conv_bf16(const float* __restrict__ in,
                                                 unsigned short* __restrict__ out) {
  int id = blockIdx.x * 256 + threadIdx.x;   // 16,384,000 / 4 = 4,096,000 exact
  float4 v = *(const float4*)&in[(size_t)id * 4];
  unsigned int a = (unsigned int)f2bf(v.x) | ((unsigned int)f2bf(v.y) << 16);
  unsigned int b = (unsigned int)f2bf(v.z) | ((unsigned int)f2bf(v.w) << 16);
  *(uint2*)&out[(size_t)id * 4] = make_uint2(a, b);
}

// Whh [1024][256] f32 -> WP [128][1024] uint, packing bf16(Whh[j][2k2]),bf16(Whh[j][2k2+1])
__global__ __launch_bounds__(256) void pack_whh(const float* __restrict__ in,
                                                unsigned int* __restrict__ out) {
  int id = blockIdx.x * 256 + threadIdx.x;   // 131,072 exact
  int j = id & 1023, k2 = id >> 10;
  float2 v = *(const float2*)&in[j * 256 + k2 * 2];
  out[k2 * 1024 + j] = (unsigned int)f2bf(v.x) | ((unsigned int)f2bf(v.y) << 16);
}

// Wih1 [1024][256] f32 -> W1T [256][1024] f32
__global__ __launch_bounds__(256) void transpose_f32(const float* __restrict__ in,
                                                     float* __restrict__ out) {
  int id = blockIdx.x * 256 + threadIdx.x;
  int j = id & 1023, k = id >> 10;
  out[id] = in[j * 256 + k];
}

// ---------------- GCN: separable edge aggregation, fixed-point int LDS atomics ----------------
// agg[n,f] = W[f]*A[n] + b[f]*D[n],  A = sum dist*x[src], D = sum dist
#define FXSCALE 1048576.f        // 2^20
#define FXINV   (1.f / 1048576.f)

__global__ __launch_bounds__(1024) void gcn_kernel(
    const float* __restrict__ x, const int* __restrict__ ei, const float* __restrict__ ed,
    const float* __restrict__ Wg, const float* __restrict__ bg,
    unsigned short* __restrict__ G) {
  __shared__ float xs[2000];
  __shared__ int Ai[2000];
  __shared__ int Di[2000];
  int bs = blockIdx.x;
  int tid = threadIdx.x;
  for (int i = tid; i < 2000; i += 1024) {
    xs[i] = x[(size_t)bs * 2000 + i];
    Ai[i] = 0; Di[i] = 0;
  }
  __syncthreads();
  const int* srcp = ei + (size_t)bs * 32000;
  const int* dstp = srcp + 16000;
  const float* dp = ed + (size_t)bs * 16000;
  // 16000 edges = 4000 int4 groups
  for (int i = tid; i < 4000; i += 1024) {
    int4 s4 = ((const int4*)srcp)[i];
    int4 d4 = ((const int4*)dstp)[i];
    float4 w4 = ((const float4*)dp)[i];
    atomicAdd(&Ai[d4.x], __float2int_rn(w4.x * xs[s4.x] * FXSCALE));
    atomicAdd(&Di[d4.x], __float2int_rn(w4.x * FXSCALE));
    atomicAdd(&Ai[d4.y], __float2int_rn(w4.y * xs[s4.y] * FXSCALE));
    atomicAdd(&Di[d4.y], __float2int_rn(w4.y * FXSCALE));
    atomicAdd(&Ai[d4.z], __float2int_rn(w4.z * xs[s4.z] * FXSCALE));
    atomicAdd(&Di[d4.z], __float2int_rn(w4.z * FXSCALE));
    atomicAdd(&Ai[d4.w], __float2int_rn(w4.w * xs[s4.w] * FXSCALE));
    atomicAdd(&Di[d4.w], __float2int_rn(w4.w * FXSCALE));
  }
  __syncthreads();
  float wreg[8], breg[8];
#pragma unroll
  for (int f = 0; f < 8; ++f) { wreg[f] = Wg[f]; breg[f] = bg[f]; }
  for (int n = tid; n < 2000; n += 1024) {
    float a  = (float)Ai[n] * FXINV;
    float dd = (float)Di[n] * FXINV;
    unsigned int u[4];
#pragma unroll
    for (int p = 0; p < 4; ++p) {
      float v0 = tanh_fast(wreg[2 * p] * a + breg[2 * p] * dd);
      float v1 = tanh_fast(wreg[2 * p + 1] * a + breg[2 * p + 1] * dd);
      u[p] = (unsigned int)f2bf(v0) | ((unsigned int)f2bf(v1) << 16);
    }
    *(uint4*)&G[(size_t)bs * 16000 + n * 8] = make_uint4(u[0], u[1], u[2], u[3]);
  }
}

// ---------------- big MFMA GEMM: Zpart[p] = G @ W0^T (split-K) ----------------
__global__ __launch_bounds__(256) void gemm_bt(
    const unsigned short* __restrict__ A, const unsigned short* __restrict__ B,
    float* __restrict__ Cp) {
  __shared__ __align__(16) unsigned short As[128 * 32];
  __shared__ __align__(16) unsigned short Bs[128 * 32];
  const int K = 16000;
  int nt = blockIdx.x;
  int mt = blockIdx.y;
  int ks = blockIdx.z;
  int m0 = mt * 128, n0 = nt * 128;
  int tid = threadIdx.x;
  int lane = tid & 63;
  int w = tid >> 6;
  int wm = (w >> 1) * 64, wn = (w & 1) * 64;
  int fr = lane & 15;
  int kg = lane >> 4;

  f32x4 acc[4][4] = {};
  const unsigned short* Ag = A + (size_t)m0 * K + ks * 1600;
  const unsigned short* Bg = B + (size_t)n0 * K + ks * 1600;

  for (int kk = 0; kk < 1600; kk += 32) {
#pragma unroll
    for (int q = 0; q < 2; ++q) {
      int c = q * 256 + tid;
      int row = c >> 2;
      int ko = (c & 3) * 8;
      *(uint4*)&As[c * 8] = *(const uint4*)&Ag[(size_t)row * K + kk + ko];
      *(uint4*)&Bs[c * 8] = *(const uint4*)&Bg[(size_t)row * K + kk + ko];
    }
    __syncthreads();
    bf16x8 aF[4], bF[4];
#pragma unroll
    for (int i = 0; i < 4; ++i)
      aF[i] = *(const bf16x8*)&As[(wm + i * 16 + fr) * 32 + kg * 8];
#pragma unroll
    for (int i = 0; i < 4; ++i)
      bF[i] = *(const bf16x8*)&Bs[(wn + i * 16 + fr) * 32 + kg * 8];
#pragma unroll
    for (int i = 0; i < 4; ++i)
#pragma unroll
      for (int j = 0; j < 4; ++j)
        acc[i][j] = __builtin_amdgcn_mfma_f32_16x16x32_bf16(aF[i], bF[j], acc[i][j], 0, 0, 0);
    __syncthreads();
  }
  float* Co = Cp + (size_t)ks * 768 * 1024;
  int mr = (lane >> 4) * 4;
#pragma unroll
  for (int i = 0; i < 4; ++i)
#pragma unroll
    for (int j = 0; j < 4; ++j) {
      int n = n0 + wn + j * 16 + fr;
#pragma unroll
      for (int r = 0; r < 4; ++r) {
        int m = m0 + wm + i * 16 + mr + r;
        Co[(size_t)m * 1024 + n] = acc[i][j][r];
      }
    }
}

__global__ __launch_bounds__(256) void reduce_z0(
    const float* __restrict__ Cp, const float* __restrict__ bih,
    const float* __restrict__ bhh, float* __restrict__ Z0) {
  int id = blockIdx.x * 256 + threadIdx.x;   // 786,432 exact
  float s = bih[id & 1023] + bhh[id & 1023];
#pragma unroll
  for (int p = 0; p < 10; ++p) s += Cp[(size_t)p * 786432 + id];
  Z0[id] = s;
}

// ---------------- LSTM scan: 4 blocks per batch, LDS-resident weights ----------------
__global__ __launch_bounds__(512) void lstm_scan_sync(
    const float* __restrict__ Z, const unsigned int* __restrict__ WP,
    float* __restrict__ Hex, int* __restrict__ cnt, float* __restrict__ lastOut) {
  __shared__ unsigned int Wl[128 * 256];   // 128 KB: this block's 256 gate columns
  __shared__ float h_lds[256];
  __shared__ float g_lds[512];
  int b  = blockIdx.x >> 2;     // batch
  int g  = blockIdx.x & 3;      // group (owns gate cols {q*256 + g*64 + 0..63})
  int tid = threadIdx.x;
  int c  = tid & 255;           // local column 0..255
  int kh = tid >> 8;            // k-half 0/1
  int q  = c >> 6;              // gate type
  int r  = c & 63;
  int j0 = g * 64;
  int col = q * 256 + j0 + r;   // global gate column

  for (int idx = tid; idx < 128 * 256; idx += 512) {
    int k2 = idx >> 8;
    int cc = idx & 255;
    Wl[idx] = WP[k2 * 1024 + (cc >> 6) * 256 + j0 + (cc & 63)];
  }
  if (tid < 256) h_lds[tid] = 0.f;
  __syncthreads();

  float cst = 0.f;
  const size_t b24 = (size_t)b * 24;
  const float* Zb = Z + b24 * 1024 + col;
  const int kbase = kh * 64;

  for (int t = 0; t < 24; ++t) {
    float acc = (kh == 0) ? Zb[t * 1024] : 0.f;
#pragma unroll 8
    for (int k2 = 0; k2 < 64; ++k2) {
      int kk = kbase + k2;
      unsigned int w2 = Wl[kk * 256 + c];
      float2 h2 = *(const float2*)&h_lds[kk * 2];
      acc += __uint_as_float(w2 << 16) * h2.x + __uint_as_float(w2 & 0xFFFF0000u) * h2.y;
    }
    g_lds[tid] = acc;
    __syncthreads();
    if (tid < 64) {
      float ig = sigmf(g_lds[tid]       + g_lds[tid + 256]);
      float fg = sigmf(g_lds[tid + 64]  + g_lds[tid + 320]);
      float gg = tanh_fast(g_lds[tid + 128] + g_lds[tid + 384]);
      float og = sigmf(g_lds[tid + 192] + g_lds[tid + 448]);
      cst = fg * cst + ig * gg;
      float h = og * tanh_fast(cst);
      __hip_atomic_store(&Hex[(b24 + t) * 256 + j0 + tid], h,
                         __ATOMIC_RELAXED, __HIP_MEMORY_SCOPE_AGENT);
      if (lastOut != nullptr && t == 23)
        lastOut[b * 256 + j0 + tid] = tanh_fast(h);
    }
    if (t == 23) break;
    __syncthreads();
    if (tid == 0) {
      __hip_atomic_fetch_add(&cnt[b * 24 + t], 1, __ATOMIC_RELEASE, __HIP_MEMORY_SCOPE_AGENT);
      while (__hip_atomic_load(&cnt[b * 24 + t], __ATOMIC_ACQUIRE,
                               __HIP_MEMORY_SCOPE_AGENT) < 4)
        __builtin_amdgcn_s_sleep(2);
    }
    __syncthreads();
    if (tid < 256)
      h_lds[tid] = __hip_atomic_load(&Hex[(b24 + t) * 256 + tid],
                                     __ATOMIC_RELAXED, __HIP_MEMORY_SCOPE_AGENT);
    __syncthreads();
  }
}

// ---------------- Z1 = H1 @ Wih1^T + biases ----------------
__global__ __launch_bounds__(256) void gemm_z1(
    const float* __restrict__ H1, const float* __restrict__ W1T,
    const float* __restrict__ bih, const float* __restrict__ bhh,
    float* __restrict__ Z1) {
  __shared__ float Hs[16][256];
  int tid = threadIdx.x;
  int n = blockIdx.x * 256 + tid;
  int m0 = blockIdx.y * 16;
  for (int i = tid; i < 16 * 256; i += 256)
    Hs[i >> 8][i & 255] = H1[(size_t)(m0 + (i >> 8)) * 256 + (i & 255)];
  __syncthreads();
  float acc[16] = {};
  for (int k = 0; k < 256; ++k) {
    float wv = W1T[k * 1024 + n];
#pragma unroll
    for (int m = 0; m < 16; ++m) acc[m] += Hs[m][k] * wv;
  }
  float bias = bih[n] + bhh[n];
#pragma unroll
  for (int m = 0; m < 16; ++m) Z1[(size_t)(m0 + m) * 1024 + n] = acc[m] + bias;
}

// ---------------- fc: out = last @ fc_W^T + fc_b ----------------
__global__ __launch_bounds__(256) void fc_kernel(
    const float* __restrict__ last, const float* __restrict__ fcW,
    const float* __restrict__ fcb, float* __restrict__ out) {
  __shared__ float ls[8][256];
  int tid = threadIdx.x;
  int o = blockIdx.x * 256 + tid;
  int b0 = blockIdx.y * 8;
  for (int i = tid; i < 2048; i += 256)
    ls[i >> 8][i & 255] = last[(b0 + (i >> 8)) * 256 + (i & 255)];
  __syncthreads();
  if (o < 8000) {
    float acc[8] = {};
    for (int k = 0; k < 256; k += 4) {
      float4 wv = *(const float4*)&fcW[(size_t)o * 256 + k];
#pragma unroll
      for (int b = 0; b < 8; ++b)
        acc[b] += wv.x * ls[b][k] + wv.y * ls[b][k + 1] + wv.z * ls[b][k + 2] + wv.w * ls[b][k + 3];
    }
    float bias = fcb[o];
#pragma unroll
    for (int b = 0; b < 8; ++b) out[(size_t)(b0 + b) * 8000 + o] = acc[b] + bias;
  }
}

// ---------------- launch ----------------
extern "C" void kernel_launch(void* const* d_in, const int* in_sizes, int n_in,
                              void* d_out, int out_size, void* d_ws, size_t ws_size,
                              hipStream_t stream) {
  const float* x    = (const float*)d_in[0];
  const int*   ei   = (const int*)d_in[1];
  const float* ed   = (const float*)d_in[2];
  const float* Wg   = (const float*)d_in[3];
  const float* bg   = (const float*)d_in[4];
  const float* Wih0 = (const float*)d_in[5];
  const float* Whh0 = (const float*)d_in[6];
  const float* bih0 = (const float*)d_in[7];
  const float* bhh0 = (const float*)d_in[8];
  const float* Wih1 = (const float*)d_in[9];
  const float* Whh1 = (const float*)d_in[10];
  const float* bih1 = (const float*)d_in[11];
  const float* bhh1 = (const float*)d_in[12];
  const float* fcW  = (const float*)d_in[13];
  const float* fcb  = (const float*)d_in[14];
  float* out = (float*)d_out;

  char* ws = (char*)d_ws;
  unsigned short* Gbf  = (unsigned short*)(ws);              // 24,576,000
  unsigned short* W0bf = (unsigned short*)(ws + 24576000);   // 32,768,000
  float* Zpart = (float*)(ws + 57344000);                    // 31,457,280
  float* Z0    = (float*)(ws + 88801280);                    //  3,145,728
  unsigned int* WP0 = (unsigned int*)(ws + 91947008);        //    524,288
  unsigned int* WP1 = (unsigned int*)(ws + 92471296);        //    524,288
  float* W1T   = (float*)(ws + 92995584);                    //  1,048,576
  float* H1    = (float*)(ws + 94044160);                    //    786,432
  float* Z1    = (float*)(ws + 94830592);                    //  3,145,728
  float* lastb = (float*)(ws + 97976320);                    //     32,768
  float* Hs1   = (float*)(ws + 98009088);                    //    786,432
  int*   cnt   = (int*)(ws + 98795520);                      //      8,192  (end ~98.8 MB)

  hipMemsetAsync(cnt, 0, 8192, stream);
  conv_bf16<<<16000, 256, 0, stream>>>(Wih0, W0bf);
  pack_whh<<<512, 256, 0, stream>>>(Whh0, WP0);
  pack_whh<<<512, 256, 0, stream>>>(Whh1, WP1);
  transpose_f32<<<1024, 256, 0, stream>>>(Wih1, W1T);
  gcn_kernel<<<768, 1024, 0, stream>>>(x, ei, ed, Wg, bg, Gbf);
  gemm_bt<<<dim3(8, 6, 10), 256, 0, stream>>>(Gbf, W0bf, Zpart);
  reduce_z0<<<3072, 256, 0, stream>>>(Zpart, bih0, bhh0, Z0);
  lstm_scan_sync<<<128, 512, 0, stream>>>(Z0, WP0, H1, cnt, nullptr);
  gemm_z1<<<dim3(4, 48), 256, 0, stream>>>(H1, W1T, bih1, bhh1, Z1);
  lstm_scan_sync<<<128, 512, 0, stream>>>(Z1, WP1, Hs1, cnt + 768, lastb);
  fc_kernel<<<dim3(32, 4), 256, 0, stream>>>(lastb, fcW, fcb, out);
}

// Round 6
// 352.223 us; speedup vs baseline: 2.1441x; 1.1717x over previous
//
#include <hip/hip_runtime.h>

#define DEVINL __device__ __forceinline__

typedef __attribute__((ext_vector_type(8))) short bf16x8;
typedef __attribute__((ext_vector_type(4))) float f32x4;
typedef _Float16 half2_t __attribute__((ext_vector_type(2)));

DEVINL unsigned short f2bf(float f) {
  unsigned int u = __float_as_uint(f);
  u += 0x7FFFu + ((u >> 16) & 1u);
  return (unsigned short)(u >> 16);
}
DEVINL float sigmf(float x) { return 1.f / (1.f + __expf(-x)); }
DEVINL float tanh_fast(float x) { float e = __expf(2.f * x); return 1.f - 2.f / (e + 1.f); }

DEVINL float fdot2u(unsigned int h, unsigned int w, float acc) {
  return __builtin_amdgcn_fdot2(__builtin_bit_cast(half2_t, h),
                                __builtin_bit_cast(half2_t, w), acc, false);
}

// ---------------- conversion / pack helpers ----------------

__global__ __launch_bounds__(256) void conv_bf16(const float* __restrict__ in,
                                                 unsigned short* __restrict__ out) {
  int id = blockIdx.x * 256 + threadIdx.x;   // 4,096,000 exact
  float4 v = *(const float4*)&in[(size_t)id * 4];
  unsigned int a = (unsigned int)f2bf(v.x) | ((unsigned int)f2bf(v.y) << 16);
  unsigned int b = (unsigned int)f2bf(v.z) | ((unsigned int)f2bf(v.w) << 16);
  *(uint2*)&out[(size_t)id * 4] = make_uint2(a, b);
}

// Whh [1024][256] f32 -> WPK [512 threads][2 cols][128 k-pairs] packed f16
__global__ __launch_bounds__(256) void pack_whh_f16(const float* __restrict__ in,
                                                    unsigned int* __restrict__ out) {
  int id = blockIdx.x * 256 + threadIdx.x;   // 131,072 exact
  int t = id >> 8;
  int cs = (id >> 7) & 1;
  int u = id & 127;
  int col = t + cs * 512;
  float a = in[col * 256 + 2 * u];
  float b = in[col * 256 + 2 * u + 1];
  unsigned short ha = __builtin_bit_cast(unsigned short, (_Float16)a);
  unsigned short hb = __builtin_bit_cast(unsigned short, (_Float16)b);
  out[id] = (unsigned int)ha | ((unsigned int)hb << 16);
}

// Wih1 [1024][256] f32 -> W1T [256][1024] f32
__global__ __launch_bounds__(256) void transpose_f32(const float* __restrict__ in,
                                                     float* __restrict__ out) {
  int id = blockIdx.x * 256 + threadIdx.x;
  int j = id & 1023, k = id >> 10;
  out[id] = in[j * 256 + k];
}

// ---------------- GCN: separable edge aggregation, fixed-point int LDS atomics ----------------
#define FXSCALE 1048576.f        // 2^20
#define FXINV   (1.f / 1048576.f)

__global__ __launch_bounds__(1024) void gcn_kernel(
    const float* __restrict__ x, const int* __restrict__ ei, const float* __restrict__ ed,
    const float* __restrict__ Wg, const float* __restrict__ bg,
    unsigned short* __restrict__ G) {
  __shared__ float xs[2000];
  __shared__ int Ai[2000];
  __shared__ int Di[2000];
  int bs = blockIdx.x;
  int tid = threadIdx.x;
  for (int i = tid; i < 2000; i += 1024) {
    xs[i] = x[(size_t)bs * 2000 + i];
    Ai[i] = 0; Di[i] = 0;
  }
  __syncthreads();
  const int* srcp = ei + (size_t)bs * 32000;
  const int* dstp = srcp + 16000;
  const float* dp = ed + (size_t)bs * 16000;
  for (int i = tid; i < 4000; i += 1024) {
    int4 s4 = ((const int4*)srcp)[i];
    int4 d4 = ((const int4*)dstp)[i];
    float4 w4 = ((const float4*)dp)[i];
    atomicAdd(&Ai[d4.x], __float2int_rn(w4.x * xs[s4.x] * FXSCALE));
    atomicAdd(&Di[d4.x], __float2int_rn(w4.x * FXSCALE));
    atomicAdd(&Ai[d4.y], __float2int_rn(w4.y * xs[s4.y] * FXSCALE));
    atomicAdd(&Di[d4.y], __float2int_rn(w4.y * FXSCALE));
    atomicAdd(&Ai[d4.z], __float2int_rn(w4.z * xs[s4.z] * FXSCALE));
    atomicAdd(&Di[d4.z], __float2int_rn(w4.z * FXSCALE));
    atomicAdd(&Ai[d4.w], __float2int_rn(w4.w * xs[s4.w] * FXSCALE));
    atomicAdd(&Di[d4.w], __float2int_rn(w4.w * FXSCALE));
  }
  __syncthreads();
  float wreg[8], breg[8];
#pragma unroll
  for (int f = 0; f < 8; ++f) { wreg[f] = Wg[f]; breg[f] = bg[f]; }
  for (int n = tid; n < 2000; n += 1024) {
    float a  = (float)Ai[n] * FXINV;
    float dd = (float)Di[n] * FXINV;
    unsigned int u[4];
#pragma unroll
    for (int p = 0; p < 4; ++p) {
      float v0 = tanh_fast(wreg[2 * p] * a + breg[2 * p] * dd);
      float v1 = tanh_fast(wreg[2 * p + 1] * a + breg[2 * p + 1] * dd);
      u[p] = (unsigned int)f2bf(v0) | ((unsigned int)f2bf(v1) << 16);
    }
    *(uint4*)&G[(size_t)bs * 16000 + n * 8] = make_uint4(u[0], u[1], u[2], u[3]);
  }
}

// ---------------- big MFMA GEMM: Zpart[p] = G @ W0^T (split-K) ----------------
__global__ __launch_bounds__(256) void gemm_bt(
    const unsigned short* __restrict__ A, const unsigned short* __restrict__ B,
    float* __restrict__ Cp) {
  __shared__ __align__(16) unsigned short As[128 * 32];
  __shared__ __align__(16) unsigned short Bs[128 * 32];
  const int K = 16000;
  int nt = blockIdx.x;
  int mt = blockIdx.y;
  int ks = blockIdx.z;
  int m0 = mt * 128, n0 = nt * 128;
  int tid = threadIdx.x;
  int lane = tid & 63;
  int w = tid >> 6;
  int wm = (w >> 1) * 64, wn = (w & 1) * 64;
  int fr = lane & 15;
  int kg = lane >> 4;

  f32x4 acc[4][4] = {};
  const unsigned short* Ag = A + (size_t)m0 * K + ks * 1600;
  const unsigned short* Bg = B + (size_t)n0 * K + ks * 1600;

  for (int kk = 0; kk < 1600; kk += 32) {
#pragma unroll
    for (int q = 0; q < 2; ++q) {
      int c = q * 256 + tid;
      int row = c >> 2;
      int ko = (c & 3) * 8;
      *(uint4*)&As[c * 8] = *(const uint4*)&Ag[(size_t)row * K + kk + ko];
      *(uint4*)&Bs[c * 8] = *(const uint4*)&Bg[(size_t)row * K + kk + ko];
    }
    __syncthreads();
    bf16x8 aF[4], bF[4];
#pragma unroll
    for (int i = 0; i < 4; ++i)
      aF[i] = *(const bf16x8*)&As[(wm + i * 16 + fr) * 32 + kg * 8];
#pragma unroll
    for (int i = 0; i < 4; ++i)
      bF[i] = *(const bf16x8*)&Bs[(wn + i * 16 + fr) * 32 + kg * 8];
#pragma unroll
    for (int i = 0; i < 4; ++i)
#pragma unroll
      for (int j = 0; j < 4; ++j)
        acc[i][j] = __builtin_amdgcn_mfma_f32_16x16x32_bf16(aF[i], bF[j], acc[i][j], 0, 0, 0);
    __syncthreads();
  }
  float* Co = Cp + (size_t)ks * 768 * 1024;
  int mr = (lane >> 4) * 4;
#pragma unroll
  for (int i = 0; i < 4; ++i)
#pragma unroll
    for (int j = 0; j < 4; ++j) {
      int n = n0 + wn + j * 16 + fr;
#pragma unroll
      for (int r = 0; r < 4; ++r) {
        int m = m0 + wm + i * 16 + mr + r;
        Co[(size_t)m * 1024 + n] = acc[i][j][r];
      }
    }
}

__global__ __launch_bounds__(256) void reduce_z0(
    const float* __restrict__ Cp, const float* __restrict__ bih,
    const float* __restrict__ bhh, float* __restrict__ Z0) {
  int id = blockIdx.x * 256 + threadIdx.x;   // 786,432 exact
  float s = bih[id & 1023] + bhh[id & 1023];
#pragma unroll
  for (int p = 0; p < 10; ++p) s += Cp[(size_t)p * 786432 + id];
  Z0[id] = s;
}

// ---------------- LSTM: one block per batch, weights resident in VGPR+LDS ----------------
// Z: [32*24][1024] preactivations (biases included).
// WPK: [512][2][128] packed f16 k-pairs; u<96 -> registers, u>=96 -> LDS slab.
__global__ __launch_bounds__(512, 2) void lstm_fused(
    const float* __restrict__ Z, const unsigned int* __restrict__ WPK,
    float* __restrict__ Hout, float* __restrict__ lastOut) {
  __shared__ __align__(16) unsigned int Wl[512 * 68];   // 139,264 B (68-dword stride: pad)
  __shared__ float g_lds[1024];                          // 4 KB
  __shared__ __align__(8) unsigned short h16[256];       // 512 B
  int b = blockIdx.x;
  int tid = threadIdx.x;
  int lane = tid & 63;

  // load register-resident weights (u < 96 for both cols)
  unsigned int wr0[96], wr1[96];
  const uint4* wp = (const uint4*)(WPK + (size_t)tid * 256);
#pragma unroll
  for (int q = 0; q < 24; ++q) {
    uint4 v = wp[q];
    wr0[q * 4] = v.x; wr0[q * 4 + 1] = v.y; wr0[q * 4 + 2] = v.z; wr0[q * 4 + 3] = v.w;
  }
#pragma unroll
  for (int q = 0; q < 24; ++q) {
    uint4 v = wp[32 + q];
    wr1[q * 4] = v.x; wr1[q * 4 + 1] = v.y; wr1[q * 4 + 2] = v.z; wr1[q * 4 + 3] = v.w;
  }
  // stage LDS-resident weights (u in [96,128) for both cols)
  int t68 = tid * 68;
#pragma unroll
  for (int q = 0; q < 8; ++q)
    *(uint4*)&Wl[t68 + q * 4] = wp[24 + q];          // cs0: Wl[t68 + 0..31]
#pragma unroll
  for (int q = 0; q < 8; ++q)
    *(uint4*)&Wl[t68 + 32 + q * 4] = wp[56 + q];     // cs1: Wl[t68 + 32..63]
  if (tid < 128) ((unsigned int*)h16)[tid] = 0;      // h = 0
  __syncthreads();

  float cst = 0.f;
  const size_t b24 = (size_t)b * 24;
  const float* Zb = Z + b24 * 1024 + tid;

#pragma unroll 1
  for (int t = 0; t < 24; ++t) {
    // each lane grabs its h-pair chunk; readlane broadcasts via SGPRs
    uint2 hv = *(const uint2*)&((const unsigned int*)h16)[lane * 2];
    float z0 = Zb[t * 1024];
    float z1 = Zb[t * 1024 + 512];
    float acc0 = 0.f, acc1 = 0.f;
#pragma unroll
    for (int p = 0; p < 6; ++p) {
#pragma unroll
      for (int s = 0; s < 16; ++s) {
        const int u = p * 16 + s;
        unsigned int hu = (unsigned int)__builtin_amdgcn_readlane(
            (int)((u & 1) ? hv.y : hv.x), u >> 1);
        acc0 = fdot2u(hu, wr0[u], acc0);
        acc1 = fdot2u(hu, wr1[u], acc1);
      }
    }
#pragma unroll
    for (int p = 6; p < 8; ++p) {
#pragma unroll
      for (int q = 0; q < 4; ++q) {
        uint4 wa = *(const uint4*)&Wl[t68 + ((p - 6) * 4 + q) * 4];
        uint4 wb = *(const uint4*)&Wl[t68 + 32 + ((p - 6) * 4 + q) * 4];
#pragma unroll
        for (int r = 0; r < 4; ++r) {
          const int u = p * 16 + q * 4 + r;
          unsigned int hu = (unsigned int)__builtin_amdgcn_readlane(
              (int)((u & 1) ? hv.y : hv.x), u >> 1);
          unsigned int w0r = (r == 0) ? wa.x : (r == 1) ? wa.y : (r == 2) ? wa.z : wa.w;
          unsigned int w1r = (r == 0) ? wb.x : (r == 1) ? wb.y : (r == 2) ? wb.z : wb.w;
          acc0 = fdot2u(hu, w0r, acc0);
          acc1 = fdot2u(hu, w1r, acc1);
        }
      }
    }
    g_lds[tid] = z0 + acc0;
    g_lds[tid + 512] = z1 + acc1;
    __syncthreads();
    if (tid < 256) {
      float ig = sigmf(g_lds[tid]);
      float fg = sigmf(g_lds[tid + 256]);
      float gg = tanh_fast(g_lds[tid + 512]);
      float og = sigmf(g_lds[tid + 768]);
      cst = fg * cst + ig * gg;
      float h = og * tanh_fast(cst);
      h16[tid] = __builtin_bit_cast(unsigned short, (_Float16)h);
      if (Hout) Hout[(b24 + t) * 256 + tid] = h;
      if (lastOut && t == 23) lastOut[b * 256 + tid] = tanh_fast(h);
    }
    __syncthreads();
  }
}

// ---------------- Z1 = H1 @ Wih1^T + biases ----------------
__global__ __launch_bounds__(256) void gemm_z1(
    const float* __restrict__ H1, const float* __restrict__ W1T,
    const float* __restrict__ bih, const float* __restrict__ bhh,
    float* __restrict__ Z1) {
  __shared__ float Hs[16][256];
  int tid = threadIdx.x;
  int n = blockIdx.x * 256 + tid;
  int m0 = blockIdx.y * 16;
  for (int i = tid; i < 16 * 256; i += 256)
    Hs[i >> 8][i & 255] = H1[(size_t)(m0 + (i >> 8)) * 256 + (i & 255)];
  __syncthreads();
  float acc[16] = {};
  for (int k = 0; k < 256; ++k) {
    float wv = W1T[k * 1024 + n];
#pragma unroll
    for (int m = 0; m < 16; ++m) acc[m] += Hs[m][k] * wv;
  }
  float bias = bih[n] + bhh[n];
#pragma unroll
  for (int m = 0; m < 16; ++m) Z1[(size_t)(m0 + m) * 1024 + n] = acc[m] + bias;
}

// ---------------- fc: out = last @ fc_W^T + fc_b ----------------
__global__ __launch_bounds__(256) void fc_kernel(
    const float* __restrict__ last, const float* __restrict__ fcW,
    const float* __restrict__ fcb, float* __restrict__ out) {
  __shared__ float ls[8][256];
  int tid = threadIdx.x;
  int o = blockIdx.x * 256 + tid;
  int b0 = blockIdx.y * 8;
  for (int i = tid; i < 2048; i += 256)
    ls[i >> 8][i & 255] = last[(b0 + (i >> 8)) * 256 + (i & 255)];
  __syncthreads();
  if (o < 8000) {
    float acc[8] = {};
    for (int k = 0; k < 256; k += 4) {
      float4 wv = *(const float4*)&fcW[(size_t)o * 256 + k];
#pragma unroll
      for (int b = 0; b < 8; ++b)
        acc[b] += wv.x * ls[b][k] + wv.y * ls[b][k + 1] + wv.z * ls[b][k + 2] + wv.w * ls[b][k + 3];
    }
    float bias = fcb[o];
#pragma unroll
    for (int b = 0; b < 8; ++b) out[(size_t)(b0 + b) * 8000 + o] = acc[b] + bias;
  }
}

// ---------------- launch ----------------
extern "C" void kernel_launch(void* const* d_in, const int* in_sizes, int n_in,
                              void* d_out, int out_size, void* d_ws, size_t ws_size,
                              hipStream_t stream) {
  const float* x    = (const float*)d_in[0];
  const int*   ei   = (const int*)d_in[1];
  const float* ed   = (const float*)d_in[2];
  const float* Wg   = (const float*)d_in[3];
  const float* bg   = (const float*)d_in[4];
  const float* Wih0 = (const float*)d_in[5];
  const float* Whh0 = (const float*)d_in[6];
  const float* bih0 = (const float*)d_in[7];
  const float* bhh0 = (const float*)d_in[8];
  const float* Wih1 = (const float*)d_in[9];
  const float* Whh1 = (const float*)d_in[10];
  const float* bih1 = (const float*)d_in[11];
  const float* bhh1 = (const float*)d_in[12];
  const float* fcW  = (const float*)d_in[13];
  const float* fcb  = (const float*)d_in[14];
  float* out = (float*)d_out;

  char* ws = (char*)d_ws;
  unsigned short* Gbf  = (unsigned short*)(ws);              // 24,576,000
  unsigned short* W0bf = (unsigned short*)(ws + 24576000);   // 32,768,000
  float* Zpart = (float*)(ws + 57344000);                    // 31,457,280
  float* Z0    = (float*)(ws + 88801280);                    //  3,145,728
  unsigned int* WPK0 = (unsigned int*)(ws + 91947008);       //    524,288
  unsigned int* WPK1 = (unsigned int*)(ws + 92471296);       //    524,288
  float* W1T   = (float*)(ws + 92995584);                    //  1,048,576
  float* H1    = (float*)(ws + 94044160);                    //    786,432
  float* Z1    = (float*)(ws + 94830592);                    //  3,145,728
  float* lastb = (float*)(ws + 97976320);                    //     32,768  (end ~98 MB)

  conv_bf16<<<16000, 256, 0, stream>>>(Wih0, W0bf);
  pack_whh_f16<<<512, 256, 0, stream>>>(Whh0, WPK0);
  pack_whh_f16<<<512, 256, 0, stream>>>(Whh1, WPK1);
  transpose_f32<<<1024, 256, 0, stream>>>(Wih1, W1T);
  gcn_kernel<<<768, 1024, 0, stream>>>(x, ei, ed, Wg, bg, Gbf);
  gemm_bt<<<dim3(8, 6, 10), 256, 0, stream>>>(Gbf, W0bf, Zpart);
  reduce_z0<<<3072, 256, 0, stream>>>(Zpart, bih0, bhh0, Z0);
  lstm_fused<<<32, 512, 0, stream>>>(Z0, WPK0, H1, nullptr);
  gemm_z1<<<dim3(4, 48), 256, 0, stream>>>(H1, W1T, bih1, bhh1, Z1);
  lstm_fused<<<32, 512, 0, stream>>>(Z1, WPK1, nullptr, lastb);
  fc_kernel<<<dim3(32, 4), 256, 0, stream>>>(lastb, fcW, fcb, out);
}

// Round 7
// 283.716 us; speedup vs baseline: 2.6618x; 1.2415x over previous
//
#include <hip/hip_runtime.h>

#define DEVINL __device__ __forceinline__

typedef __attribute__((ext_vector_type(8))) short bf16x8;
typedef __attribute__((ext_vector_type(4))) float f32x4;
typedef _Float16 half2_t __attribute__((ext_vector_type(2)));
typedef _Float16 f16x8 __attribute__((ext_vector_type(8)));

DEVINL unsigned short f2bf(float f) {
  unsigned int u = __float_as_uint(f);
  u += 0x7FFFu + ((u >> 16) & 1u);
  return (unsigned short)(u >> 16);
}
DEVINL float sigmf(float x) { return 1.f / (1.f + __expf(-x)); }
DEVINL float tanh_fast(float x) { float e = __expf(2.f * x); return 1.f - 2.f / (e + 1.f); }

DEVINL float fdot2u(unsigned int h, unsigned int w, float acc) {
  return __builtin_amdgcn_fdot2(__builtin_bit_cast(half2_t, h),
                                __builtin_bit_cast(half2_t, w), acc, false);
}

// ---------------- conversion / pack helpers ----------------

__global__ __launch_bounds__(256) void conv_bf16(const float* __restrict__ in,
                                                 unsigned short* __restrict__ out) {
  int id = blockIdx.x * 256 + threadIdx.x;   // 4,096,000 exact
  float4 v = *(const float4*)&in[(size_t)id * 4];
  unsigned int a = (unsigned int)f2bf(v.x) | ((unsigned int)f2bf(v.y) << 16);
  unsigned int b = (unsigned int)f2bf(v.z) | ((unsigned int)f2bf(v.w) << 16);
  *(uint2*)&out[(size_t)id * 4] = make_uint2(a, b);
}

// elementwise f32 -> f16 (Wih1 [1024][256] stays row-major)
__global__ __launch_bounds__(256) void conv_f16(const float* __restrict__ in,
                                                unsigned short* __restrict__ out) {
  int id = blockIdx.x * 256 + threadIdx.x;   // 262,144 exact
  out[id] = __builtin_bit_cast(unsigned short, (_Float16)in[id]);
}

// Whh [1024][256] f32 -> WPK [512 threads][2 cols][128 k-pairs] packed f16
__global__ __launch_bounds__(256) void pack_whh_f16(const float* __restrict__ in,
                                                    unsigned int* __restrict__ out) {
  int id = blockIdx.x * 256 + threadIdx.x;   // 131,072 exact
  int t = id >> 8;
  int cs = (id >> 7) & 1;
  int u = id & 127;
  int col = t + cs * 512;
  float a = in[col * 256 + 2 * u];
  float b = in[col * 256 + 2 * u + 1];
  unsigned short ha = __builtin_bit_cast(unsigned short, (_Float16)a);
  unsigned short hb = __builtin_bit_cast(unsigned short, (_Float16)b);
  out[id] = (unsigned int)ha | ((unsigned int)hb << 16);
}

// ---------------- GCN: separable edge aggregation, fixed-point int LDS atomics ----------------
#define FXSCALE 1048576.f        // 2^20
#define FXINV   (1.f / 1048576.f)

__global__ __launch_bounds__(1024) void gcn_kernel(
    const float* __restrict__ x, const int* __restrict__ ei, const float* __restrict__ ed,
    const float* __restrict__ Wg, const float* __restrict__ bg,
    unsigned short* __restrict__ G) {
  __shared__ float xs[2000];
  __shared__ int Ai[2000];
  __shared__ int Di[2000];
  int bs = blockIdx.x;
  int tid = threadIdx.x;
  for (int i = tid; i < 2000; i += 1024) {
    xs[i] = x[(size_t)bs * 2000 + i];
    Ai[i] = 0; Di[i] = 0;
  }
  __syncthreads();
  const int* srcp = ei + (size_t)bs * 32000;
  const int* dstp = srcp + 16000;
  const float* dp = ed + (size_t)bs * 16000;
  for (int i = tid; i < 4000; i += 1024) {
    int4 s4 = ((const int4*)srcp)[i];
    int4 d4 = ((const int4*)dstp)[i];
    float4 w4 = ((const float4*)dp)[i];
    atomicAdd(&Ai[d4.x], __float2int_rn(w4.x * xs[s4.x] * FXSCALE));
    atomicAdd(&Di[d4.x], __float2int_rn(w4.x * FXSCALE));
    atomicAdd(&Ai[d4.y], __float2int_rn(w4.y * xs[s4.y] * FXSCALE));
    atomicAdd(&Di[d4.y], __float2int_rn(w4.y * FXSCALE));
    atomicAdd(&Ai[d4.z], __float2int_rn(w4.z * xs[s4.z] * FXSCALE));
    atomicAdd(&Di[d4.z], __float2int_rn(w4.z * FXSCALE));
    atomicAdd(&Ai[d4.w], __float2int_rn(w4.w * xs[s4.w] * FXSCALE));
    atomicAdd(&Di[d4.w], __float2int_rn(w4.w * FXSCALE));
  }
  __syncthreads();
  float wreg[8], breg[8];
#pragma unroll
  for (int f = 0; f < 8; ++f) { wreg[f] = Wg[f]; breg[f] = bg[f]; }
  for (int n = tid; n < 2000; n += 1024) {
    float a  = (float)Ai[n] * FXINV;
    float dd = (float)Di[n] * FXINV;
    unsigned int u[4];
#pragma unroll
    for (int p = 0; p < 4; ++p) {
      float v0 = tanh_fast(wreg[2 * p] * a + breg[2 * p] * dd);
      float v1 = tanh_fast(wreg[2 * p + 1] * a + breg[2 * p + 1] * dd);
      u[p] = (unsigned int)f2bf(v0) | ((unsigned int)f2bf(v1) << 16);
    }
    *(uint4*)&G[(size_t)bs * 16000 + n * 8] = make_uint4(u[0], u[1], u[2], u[3]);
  }
}

// ---------------- big MFMA GEMM: Zpart[p] = G @ W0^T (split-K) ----------------
__global__ __launch_bounds__(256) void gemm_bt(
    const unsigned short* __restrict__ A, const unsigned short* __restrict__ B,
    float* __restrict__ Cp) {
  __shared__ __align__(16) unsigned short As[128 * 32];
  __shared__ __align__(16) unsigned short Bs[128 * 32];
  const int K = 16000;
  int nt = blockIdx.x;
  int mt = blockIdx.y;
  int ks = blockIdx.z;
  int m0 = mt * 128, n0 = nt * 128;
  int tid = threadIdx.x;
  int lane = tid & 63;
  int w = tid >> 6;
  int wm = (w >> 1) * 64, wn = (w & 1) * 64;
  int fr = lane & 15;
  int kg = lane >> 4;

  f32x4 acc[4][4] = {};
  const unsigned short* Ag = A + (size_t)m0 * K + ks * 1600;
  const unsigned short* Bg = B + (size_t)n0 * K + ks * 1600;

  for (int kk = 0; kk < 1600; kk += 32) {
#pragma unroll
    for (int q = 0; q < 2; ++q) {
      int c = q * 256 + tid;
      int row = c >> 2;
      int ko = (c & 3) * 8;
      *(uint4*)&As[c * 8] = *(const uint4*)&Ag[(size_t)row * K + kk + ko];
      *(uint4*)&Bs[c * 8] = *(const uint4*)&Bg[(size_t)row * K + kk + ko];
    }
    __syncthreads();
    bf16x8 aF[4], bF[4];
#pragma unroll
    for (int i = 0; i < 4; ++i)
      aF[i] = *(const bf16x8*)&As[(wm + i * 16 + fr) * 32 + kg * 8];
#pragma unroll
    for (int i = 0; i < 4; ++i)
      bF[i] = *(const bf16x8*)&Bs[(wn + i * 16 + fr) * 32 + kg * 8];
#pragma unroll
    for (int i = 0; i < 4; ++i)
#pragma unroll
      for (int j = 0; j < 4; ++j)
        acc[i][j] = __builtin_amdgcn_mfma_f32_16x16x32_bf16(aF[i], bF[j], acc[i][j], 0, 0, 0);
    __syncthreads();
  }
  float* Co = Cp + (size_t)ks * 768 * 1024;
  int mr = (lane >> 4) * 4;
#pragma unroll
  for (int i = 0; i < 4; ++i)
#pragma unroll
    for (int j = 0; j < 4; ++j) {
      int n = n0 + wn + j * 16 + fr;
#pragma unroll
      for (int r = 0; r < 4; ++r) {
        int m = m0 + wm + i * 16 + mr + r;
        Co[(size_t)m * 1024 + n] = acc[i][j][r];
      }
    }
}

__global__ __launch_bounds__(256) void reduce_z0(
    const float* __restrict__ Cp, const float* __restrict__ bih,
    const float* __restrict__ bhh, float* __restrict__ Z0) {
  int id = blockIdx.x * 256 + threadIdx.x;   // 786,432 exact
  float s = bih[id & 1023] + bhh[id & 1023];
#pragma unroll
  for (int p = 0; p < 10; ++p) s += Cp[(size_t)p * 786432 + id];
  Z0[id] = s;
}

// ---------------- LSTM: one block per batch, weights resident in VGPR+LDS ----------------
// Z: [32*24][1024] preactivations (biases included).
// WPK: [512][2][128] packed f16 k-pairs; u<96 -> registers, u>=96 -> LDS slab.
// Hout (optional): f16 h history [32*24][256].
__global__ __launch_bounds__(512, 2) void lstm_fused(
    const float* __restrict__ Z, const unsigned int* __restrict__ WPK,
    unsigned short* __restrict__ Hout, float* __restrict__ lastOut) {
  __shared__ __align__(16) unsigned int Wl[512 * 68];   // 139,264 B (68-dword stride: pad)
  __shared__ float g_lds[1024];                          // 4 KB
  __shared__ __align__(8) unsigned short h16[256];       // 512 B
  int b = blockIdx.x;
  int tid = threadIdx.x;
  int lane = tid & 63;

  unsigned int wr0[96], wr1[96];
  const uint4* wp = (const uint4*)(WPK + (size_t)tid * 256);
#pragma unroll
  for (int q = 0; q < 24; ++q) {
    uint4 v = wp[q];
    wr0[q * 4] = v.x; wr0[q * 4 + 1] = v.y; wr0[q * 4 + 2] = v.z; wr0[q * 4 + 3] = v.w;
  }
#pragma unroll
  for (int q = 0; q < 24; ++q) {
    uint4 v = wp[32 + q];
    wr1[q * 4] = v.x; wr1[q * 4 + 1] = v.y; wr1[q * 4 + 2] = v.z; wr1[q * 4 + 3] = v.w;
  }
  int t68 = tid * 68;
#pragma unroll
  for (int q = 0; q < 8; ++q)
    *(uint4*)&Wl[t68 + q * 4] = wp[24 + q];
#pragma unroll
  for (int q = 0; q < 8; ++q)
    *(uint4*)&Wl[t68 + 32 + q * 4] = wp[56 + q];
  if (tid < 128) ((unsigned int*)h16)[tid] = 0;
  __syncthreads();

  float cst = 0.f;
  const size_t b24 = (size_t)b * 24;
  const float* Zb = Z + b24 * 1024 + tid;

#pragma unroll 1
  for (int t = 0; t < 24; ++t) {
    uint2 hv = *(const uint2*)&((const unsigned int*)h16)[lane * 2];
    float z0 = Zb[t * 1024];
    float z1 = Zb[t * 1024 + 512];
    float acc0 = 0.f, acc1 = 0.f;
#pragma unroll
    for (int p = 0; p < 6; ++p) {
#pragma unroll
      for (int s = 0; s < 16; ++s) {
        const int u = p * 16 + s;
        unsigned int hu = (unsigned int)__builtin_amdgcn_readlane(
            (int)((u & 1) ? hv.y : hv.x), u >> 1);
        acc0 = fdot2u(hu, wr0[u], acc0);
        acc1 = fdot2u(hu, wr1[u], acc1);
      }
    }
#pragma unroll
    for (int p = 6; p < 8; ++p) {
#pragma unroll
      for (int q = 0; q < 4; ++q) {
        uint4 wa = *(const uint4*)&Wl[t68 + ((p - 6) * 4 + q) * 4];
        uint4 wb = *(const uint4*)&Wl[t68 + 32 + ((p - 6) * 4 + q) * 4];
#pragma unroll
        for (int r = 0; r < 4; ++r) {
          const int u = p * 16 + q * 4 + r;
          unsigned int hu = (unsigned int)__builtin_amdgcn_readlane(
              (int)((u & 1) ? hv.y : hv.x), u >> 1);
          unsigned int w0r = (r == 0) ? wa.x : (r == 1) ? wa.y : (r == 2) ? wa.z : wa.w;
          unsigned int w1r = (r == 0) ? wb.x : (r == 1) ? wb.y : (r == 2) ? wb.z : wb.w;
          acc0 = fdot2u(hu, w0r, acc0);
          acc1 = fdot2u(hu, w1r, acc1);
        }
      }
    }
    g_lds[tid] = z0 + acc0;
    g_lds[tid + 512] = z1 + acc1;
    __syncthreads();
    if (tid < 256) {
      float ig = sigmf(g_lds[tid]);
      float fg = sigmf(g_lds[tid + 256]);
      float gg = tanh_fast(g_lds[tid + 512]);
      float og = sigmf(g_lds[tid + 768]);
      cst = fg * cst + ig * gg;
      float h = og * tanh_fast(cst);
      unsigned short hh = __builtin_bit_cast(unsigned short, (_Float16)h);
      h16[tid] = hh;
      if (Hout) Hout[(b24 + t) * 256 + tid] = hh;
      if (lastOut && t == 23) lastOut[b * 256 + tid] = tanh_fast(h);
    }
    __syncthreads();
  }
}

// ---------------- Z1 = H1f16 @ Wih1f16^T + biases (MFMA) ----------------
// A [768][256] f16, B [1024][256] f16, Z1 [768][1024] f32
__global__ __launch_bounds__(256) void gemm_z1_mfma(
    const unsigned short* __restrict__ A, const unsigned short* __restrict__ B,
    const float* __restrict__ bih, const float* __restrict__ bhh,
    float* __restrict__ Z1) {
  __shared__ __align__(16) unsigned short As[128 * 32];
  __shared__ __align__(16) unsigned short Bs[128 * 32];
  const int K = 256;
  int nt = blockIdx.x;   // 0..7
  int mt = blockIdx.y;   // 0..5
  int m0 = mt * 128, n0 = nt * 128;
  int tid = threadIdx.x;
  int lane = tid & 63;
  int w = tid >> 6;
  int wm = (w >> 1) * 64, wn = (w & 1) * 64;
  int fr = lane & 15;
  int kg = lane >> 4;

  f32x4 acc[4][4] = {};
  const unsigned short* Ag = A + (size_t)m0 * K;
  const unsigned short* Bg = B + (size_t)n0 * K;

  for (int kk = 0; kk < 256; kk += 32) {
#pragma unroll
    for (int q = 0; q < 2; ++q) {
      int c = q * 256 + tid;
      int row = c >> 2;
      int ko = (c & 3) * 8;
      *(uint4*)&As[c * 8] = *(const uint4*)&Ag[(size_t)row * K + kk + ko];
      *(uint4*)&Bs[c * 8] = *(const uint4*)&Bg[(size_t)row * K + kk + ko];
    }
    __syncthreads();
    f16x8 aF[4], bF[4];
#pragma unroll
    for (int i = 0; i < 4; ++i)
      aF[i] = *(const f16x8*)&As[(wm + i * 16 + fr) * 32 + kg * 8];
#pragma unroll
    for (int i = 0; i < 4; ++i)
      bF[i] = *(const f16x8*)&Bs[(wn + i * 16 + fr) * 32 + kg * 8];
#pragma unroll
    for (int i = 0; i < 4; ++i)
#pragma unroll
      for (int j = 0; j < 4; ++j)
        acc[i][j] = __builtin_amdgcn_mfma_f32_16x16x32_f16(aF[i], bF[j], acc[i][j], 0, 0, 0);
    __syncthreads();
  }
  int mr = (lane >> 4) * 4;
#pragma unroll
  for (int j = 0; j < 4; ++j) {
    int n = n0 + wn + j * 16 + fr;
    float bias = bih[n] + bhh[n];
#pragma unroll
    for (int i = 0; i < 4; ++i) {
#pragma unroll
      for (int r = 0; r < 4; ++r) {
        int m = m0 + wm + i * 16 + mr + r;
        Z1[(size_t)m * 1024 + n] = acc[i][j][r] + bias;
      }
    }
  }
}

// ---------------- fc: out = last @ fc_W^T + fc_b ----------------
__global__ __launch_bounds__(256) void fc_kernel(
    const float* __restrict__ last, const float* __restrict__ fcW,
    const float* __restrict__ fcb, float* __restrict__ out) {
  __shared__ float ls[8][256];
  int tid = threadIdx.x;
  int o = blockIdx.x * 256 + tid;
  int b0 = blockIdx.y * 8;
  for (int i = tid; i < 2048; i += 256)
    ls[i >> 8][i & 255] = last[(b0 + (i >> 8)) * 256 + (i & 255)];
  __syncthreads();
  if (o < 8000) {
    float acc[8] = {};
    for (int k = 0; k < 256; k += 4) {
      float4 wv = *(const float4*)&fcW[(size_t)o * 256 + k];
#pragma unroll
      for (int b = 0; b < 8; ++b)
        acc[b] += wv.x * ls[b][k] + wv.y * ls[b][k + 1] + wv.z * ls[b][k + 2] + wv.w * ls[b][k + 3];
    }
    float bias = fcb[o];
#pragma unroll
    for (int b = 0; b < 8; ++b) out[(size_t)(b0 + b) * 8000 + o] = acc[b] + bias;
  }
}

// ---------------- launch ----------------
extern "C" void kernel_launch(void* const* d_in, const int* in_sizes, int n_in,
                              void* d_out, int out_size, void* d_ws, size_t ws_size,
                              hipStream_t stream) {
  const float* x    = (const float*)d_in[0];
  const int*   ei   = (const int*)d_in[1];
  const float* ed   = (const float*)d_in[2];
  const float* Wg   = (const float*)d_in[3];
  const float* bg   = (const float*)d_in[4];
  const float* Wih0 = (const float*)d_in[5];
  const float* Whh0 = (const float*)d_in[6];
  const float* bih0 = (const float*)d_in[7];
  const float* bhh0 = (const float*)d_in[8];
  const float* Wih1 = (const float*)d_in[9];
  const float* Whh1 = (const float*)d_in[10];
  const float* bih1 = (const float*)d_in[11];
  const float* bhh1 = (const float*)d_in[12];
  const float* fcW  = (const float*)d_in[13];
  const float* fcb  = (const float*)d_in[14];
  float* out = (float*)d_out;

  char* ws = (char*)d_ws;
  unsigned short* Gbf  = (unsigned short*)(ws);              // 24,576,000
  unsigned short* W0bf = (unsigned short*)(ws + 24576000);   // 32,768,000
  float* Zpart = (float*)(ws + 57344000);                    // 31,457,280
  float* Z0    = (float*)(ws + 88801280);                    //  3,145,728
  unsigned int* WPK0 = (unsigned int*)(ws + 91947008);       //    524,288
  unsigned int* WPK1 = (unsigned int*)(ws + 92471296);       //    524,288
  unsigned short* W1h = (unsigned short*)(ws + 92995584);    //    524,288 (f16 Wih1)
  unsigned short* H1  = (unsigned short*)(ws + 94044160);    //    393,216 (f16 H1)
  float* Z1    = (float*)(ws + 94830592);                    //  3,145,728
  float* lastb = (float*)(ws + 97976320);                    //     32,768  (end ~98 MB)

  conv_bf16<<<16000, 256, 0, stream>>>(Wih0, W0bf);
  pack_whh_f16<<<512, 256, 0, stream>>>(Whh0, WPK0);
  pack_whh_f16<<<512, 256, 0, stream>>>(Whh1, WPK1);
  conv_f16<<<1024, 256, 0, stream>>>(Wih1, (unsigned short*)W1h);
  gcn_kernel<<<768, 1024, 0, stream>>>(x, ei, ed, Wg, bg, Gbf);
  gemm_bt<<<dim3(8, 6, 10), 256, 0, stream>>>(Gbf, W0bf, Zpart);
  reduce_z0<<<3072, 256, 0, stream>>>(Zpart, bih0, bhh0, Z0);
  lstm_fused<<<32, 512, 0, stream>>>(Z0, WPK0, H1, nullptr);
  gemm_z1_mfma<<<dim3(8, 6), 256, 0, stream>>>(H1, W1h, bih1, bhh1, Z1);
  lstm_fused<<<32, 512, 0, stream>>>(Z1, WPK1, nullptr, lastb);
  fc_kernel<<<dim3(32, 4), 256, 0, stream>>>(lastb, fcW, fcb, out);
}